// Round 1
// 285.168 us; speedup vs baseline: 1.0322x; 1.0322x over previous
//
#include <hip/hip_runtime.h>

// SelfAttention: B=4 S=2048 D=1024 H=16 HD=64, causal, fp32 in/out, bf16 MFMA compute.
// R9->R10: attn softmax VALU diet (counters: VALUBusy 68% vs MfmaUtil 21.6% -> softmax
// VALU-bound). (1) exp2-domain scores: fold 0.125*log2e into the scale, all exps become
// raw v_exp_f32 (no log2e mul). (2) P->bf16 via packed v_cvt_pk_bf16_f32 inline asm
// (8 insts) instead of 16x bit-twiddle f2bf (~64 ops). (3) T13 defer-max: skip O-rescale
// (exp + 4 shfl + 16 mul) unless __any(tmax > m_i + 8); P bounded by 2^8, f32/bf16 safe.
// Everything outside attn_kernel is byte-identical to R9.

typedef __attribute__((ext_vector_type(8))) short short8_t;
typedef __attribute__((ext_vector_type(4))) short short4_t;
typedef __attribute__((ext_vector_type(4))) float float4_t;

constexpr int Bz = 4, Sq = 2048, Dm = 1024, NH = 16, HD = 64;
constexpr int LDSPITCH = 72;

#define GLOAD_LDS16(g, l)                                                      \
  __builtin_amdgcn_global_load_lds(                                            \
      (const __attribute__((address_space(1))) unsigned int*)(g),              \
      (__attribute__((address_space(3))) unsigned int*)(l), 16, 0, 0)

__device__ __forceinline__ unsigned short f2bf(float f) {
  unsigned u = __builtin_bit_cast(unsigned, f);
  u += 0x7fffu + ((u >> 16) & 1u);
  return (unsigned short)(u >> 16);
}

__device__ __forceinline__ float exp2_fast(float x) {
#if __has_builtin(__builtin_amdgcn_exp2f)
  return __builtin_amdgcn_exp2f(x);
#else
  return exp2f(x);
#endif
}

__global__ __launch_bounds__(256) void cast_x_kernel(const float* __restrict__ x,
                                                     unsigned short* __restrict__ xb) {
  size_t i = (size_t)blockIdx.x * 256 + threadIdx.x;
  float4 v = ((const float4*)x)[i];
  ushort4 o;
  o.x = f2bf(v.x); o.y = f2bf(v.y); o.z = f2bf(v.z); o.w = f2bf(v.w);
  ((ushort4*)xb)[i] = o;
}

// All four W [K=1024][N=1024] fp32 -> WT [N][K] bf16 in one launch. grid (16,16,4).
__global__ __launch_bounds__(256) void transpose_w_kernel(
    const float* __restrict__ Wq, const float* __restrict__ Wk,
    const float* __restrict__ Wv, const float* __restrict__ Wo,
    unsigned short* __restrict__ wqT, unsigned short* __restrict__ wkT,
    unsigned short* __restrict__ wvT, unsigned short* __restrict__ woT) {
  __shared__ float tile[64][65];
  int zz = blockIdx.z;
  const float* W = zz == 0 ? Wq : (zz == 1 ? Wk : (zz == 2 ? Wv : Wo));
  unsigned short* WT = zz == 0 ? wqT : (zz == 1 ? wkT : (zz == 2 ? wvT : woT));
  int n0 = blockIdx.x * 64, k0 = blockIdx.y * 64;
  int tx = threadIdx.x & 63, ty = threadIdx.x >> 6;
#pragma unroll
  for (int i = 0; i < 16; ++i) {
    int r = i * 4 + ty;
    tile[r][tx] = W[(size_t)(k0 + r) * Dm + n0 + tx];
  }
  __syncthreads();
#pragma unroll
  for (int i = 0; i < 16; ++i) {
    int r = i * 4 + ty;
    WT[(size_t)(n0 + r) * Dm + k0 + tx] = f2bf(tile[tx][r]);
  }
}

// m97-style main loop: 128x128 tile, BK=64, glds width=16, unpadded LDS.
__device__ __forceinline__ void gemm_mainloop(const unsigned short* __restrict__ A,
                                              const unsigned short* __restrict__ BT,
                                              int m0, int n0,
                                              unsigned short* lA, unsigned short* lB,
                                              float4_t acc[4][4]) {
  const int tid = threadIdx.x;
  const int lane = tid & 63, lr = lane & 15, quad = lane >> 4;
  const int wave = tid >> 6;
  const int mw = (wave >> 1) * 64, nw = (wave & 1) * 64;
  const int srow = tid >> 3;
  const int scol = (tid & 7) * 8;
  const unsigned short* ga = A + (size_t)(m0 + srow) * Dm + scol;
  const unsigned short* gb = BT + (size_t)(n0 + srow) * Dm + scol;
  unsigned short* la = lA + tid * 8;
  unsigned short* lb = lB + tid * 8;

  for (int k0 = 0; k0 < Dm; k0 += 64) {
    __syncthreads();
#pragma unroll
    for (int iss = 0; iss < 4; ++iss) {
      GLOAD_LDS16(ga + (size_t)iss * 32 * Dm + k0, la + iss * 32 * 64);
      GLOAD_LDS16(gb + (size_t)iss * 32 * Dm + k0, lb + iss * 32 * 64);
    }
    __syncthreads();
#pragma unroll
    for (int kk = 0; kk < 2; ++kk) {
      short8_t a[4], b[4];
#pragma unroll
      for (int i = 0; i < 4; ++i)
        a[i] = *(const short8_t*)(lA + (mw + i * 16 + lr) * 64 + kk * 32 + quad * 8);
#pragma unroll
      for (int j = 0; j < 4; ++j)
        b[j] = *(const short8_t*)(lB + (nw + j * 16 + lr) * 64 + kk * 32 + quad * 8);
#pragma unroll
      for (int i = 0; i < 4; ++i)
#pragma unroll
        for (int j = 0; j < 4; ++j)
          acc[i][j] = __builtin_amdgcn_mfma_f32_16x16x32_bf16(a[i], b[j], acc[i][j], 0, 0, 0);
    }
  }
}

// QKV projections. Q,K -> [B,H,S,HD]; V -> TRANSPOSED [B,H,HD,S]. grid (8,64,3)
__global__ __launch_bounds__(256) void gemm_qkv_kernel(
    const unsigned short* __restrict__ xb,
    const unsigned short* __restrict__ wqT, const unsigned short* __restrict__ wkT,
    const unsigned short* __restrict__ wvT,
    unsigned short* __restrict__ qb, unsigned short* __restrict__ kb,
    unsigned short* __restrict__ vt) {
  __shared__ unsigned short lA[128 * 64];
  __shared__ unsigned short lB[128 * 64];
  const unsigned short* WT = blockIdx.z == 0 ? wqT : (blockIdx.z == 1 ? wkT : wvT);
  unsigned short* outb = blockIdx.z == 0 ? qb : (blockIdx.z == 1 ? kb : vt);
  bool isV = blockIdx.z == 2;
  int lane = threadIdx.x & 63, wave = threadIdx.x >> 6;
  int lr = lane & 15, quad = lane >> 4;
  int m0 = blockIdx.y * 128, n0 = blockIdx.x * 128;
  int m_base = m0 + (wave >> 1) * 64;
  int n_base = n0 + (wave & 1) * 64;
  float4_t z = {0.f, 0.f, 0.f, 0.f};
  float4_t acc[4][4];
#pragma unroll
  for (int i = 0; i < 4; ++i)
#pragma unroll
    for (int j = 0; j < 4; ++j) acc[i][j] = z;
  gemm_mainloop(xb, WT, m0, n0, lA, lB, acc);
  if (isV) {
#pragma unroll
    for (int i = 0; i < 4; ++i)
#pragma unroll
      for (int j = 0; j < 4; ++j) {
        int m = m_base + i * 16 + quad * 4;
        int n = n_base + j * 16 + lr;
        int b = m >> 11, s = m & (Sq - 1);
        int h = n >> 6, hd = n & (HD - 1);
        ushort4 pk;
        pk.x = f2bf(acc[i][j][0]); pk.y = f2bf(acc[i][j][1]);
        pk.z = f2bf(acc[i][j][2]); pk.w = f2bf(acc[i][j][3]);
        *(ushort4*)(outb + (((size_t)b * NH + h) * HD + hd) * Sq + s) = pk;
      }
  } else {
#pragma unroll
    for (int i = 0; i < 4; ++i)
#pragma unroll
      for (int j = 0; j < 4; ++j)
#pragma unroll
        for (int r = 0; r < 4; ++r) {
          int m = m_base + i * 16 + quad * 4 + r;
          int n = n_base + j * 16 + lr;
          int b = m >> 11, s = m & (Sq - 1);
          int h = n >> 6, hd = n & (HD - 1);
          outb[(((size_t)b * NH + h) * Sq + s) * HD + hd] = f2bf(acc[i][j][r]);
        }
  }
}

// Output projection: ao_bf16 [8192,1024] @ Wo -> fp32 out. grid (8,64)
__global__ __launch_bounds__(256) void gemm_out_kernel(
    const unsigned short* __restrict__ ao, const unsigned short* __restrict__ woT,
    float* __restrict__ out) {
  __shared__ unsigned short lA[128 * 64];
  __shared__ unsigned short lB[128 * 64];
  int lane = threadIdx.x & 63, wave = threadIdx.x >> 6;
  int lr = lane & 15, quad = lane >> 4;
  int m0 = blockIdx.y * 128, n0 = blockIdx.x * 128;
  int m_base = m0 + (wave >> 1) * 64;
  int n_base = n0 + (wave & 1) * 64;
  float4_t z = {0.f, 0.f, 0.f, 0.f};
  float4_t acc[4][4];
#pragma unroll
  for (int i = 0; i < 4; ++i)
#pragma unroll
    for (int j = 0; j < 4; ++j) acc[i][j] = z;
  gemm_mainloop(ao, woT, m0, n0, lA, lB, acc);
#pragma unroll
  for (int i = 0; i < 4; ++i)
#pragma unroll
    for (int j = 0; j < 4; ++j)
#pragma unroll
      for (int r = 0; r < 4; ++r) {
        int m = m_base + i * 16 + quad * 4 + r;
        int n = n_base + j * 16 + lr;
        out[(size_t)m * Dm + n] = acc[i][j][r];
      }
}

// Flash attention — grid (B*H, 32), one 64-row q-tile per block, ti = 31 - blockIdx.y.
// Softmax in log2 domain; packed bf16 cvt; defer-max rescale (THR=8 in log2 domain).
__global__ __launch_bounds__(256) void attn_kernel(
    const unsigned short* __restrict__ qbuf, const unsigned short* __restrict__ kbuf,
    const unsigned short* __restrict__ vtbuf, unsigned short* __restrict__ ao) {
  __shared__ unsigned short lk[64 * LDSPITCH];
  __shared__ unsigned short lv[64 * LDSPITCH];
  int bh = blockIdx.x;
  int ti = 31 - (int)blockIdx.y;
  int wave = threadIdx.x >> 6, lane = threadIdx.x & 63;
  int lcol = lane & 15, quad = lane >> 4;
  const unsigned short* Q = qbuf + (size_t)bh * Sq * HD;
  const unsigned short* K = kbuf + (size_t)bh * Sq * HD;
  const unsigned short* Vt = vtbuf + (size_t)bh * HD * Sq;
  int b = bh >> 4, h = bh & 15;
  int srow = threadIdx.x >> 2;
  int scol = (threadIdx.x & 3) * 16;
  float4_t z = {0.f, 0.f, 0.f, 0.f};
  // scores scaled by 1/sqrt(HD) and converted to log2 domain in one multiply:
  // p = exp((s/8) - m) == exp2(s*0.125*log2e - m2)
  constexpr float kS = 0.18033688011112042f;  // 0.125 * log2(e)

  int q0w = ti * 64 + wave * 16;
  int q_global = q0w + lcol;
  short8_t qf0 = *(const short8_t*)(Q + (size_t)(q0w + lcol) * HD + quad * 8);
  short8_t qf1 = *(const short8_t*)(Q + (size_t)(q0w + lcol) * HD + 32 + quad * 8);
  float m_i = -INFINITY, l_i = 0.f;
  float4_t o[4];
#pragma unroll
  for (int f = 0; f < 4; ++f) o[f] = z;

  int nkt = ti + 1;
  for (int kt = 0; kt < nkt; ++kt) {
    int key0 = kt * 64;
    __syncthreads();
    {
      const unsigned short* kg = K + (size_t)(key0 + srow) * HD + scol;
      const unsigned short* vg = Vt + (size_t)srow * Sq + key0 + scol;
      unsigned short* kl = lk + srow * LDSPITCH + scol;
      unsigned short* vl = lv + srow * LDSPITCH + scol;
      *(short8_t*)(kl) = *(const short8_t*)(kg);
      *(short8_t*)(kl + 8) = *(const short8_t*)(kg + 8);
      *(short8_t*)(vl) = *(const short8_t*)(vg);
      *(short8_t*)(vl + 8) = *(const short8_t*)(vg + 8);
    }
    __syncthreads();

    bool need_mask = (key0 + 63 > q0w);
    float s[16];
    float tmax = -INFINITY;
#pragma unroll
    for (int s4 = 0; s4 < 4; ++s4) {
      short8_t kf0 = *(const short8_t*)(lk + (s4 * 16 + lcol) * LDSPITCH + quad * 8);
      short8_t kf1 = *(const short8_t*)(lk + (s4 * 16 + lcol) * LDSPITCH + 32 + quad * 8);
      float4_t st = z;
      st = __builtin_amdgcn_mfma_f32_16x16x32_bf16(kf0, qf0, st, 0, 0, 0);
      st = __builtin_amdgcn_mfma_f32_16x16x32_bf16(kf1, qf1, st, 0, 0, 0);
#pragma unroll
      for (int r = 0; r < 4; ++r) {
        float v = st[r] * kS;
        if (need_mask && (key0 + s4 * 16 + quad * 4 + r > q_global)) v = -INFINITY;
        s[s4 * 4 + r] = v;
        tmax = fmaxf(tmax, v);
      }
    }
    tmax = fmaxf(tmax, __shfl_xor(tmax, 16, 64));
    tmax = fmaxf(tmax, __shfl_xor(tmax, 32, 64));

    // T13 defer-max: only rescale when the running max actually grew by >8
    // (log2 domain => P bounded by 2^8 = 256; f32 psum and bf16 P are safe).
    if (__any(tmax > m_i + 8.f)) {
      float m_new = fmaxf(m_i, tmax);
      float alpha = exp2_fast(m_i - m_new);
      l_i *= alpha;
      m_i = m_new;
      float at[4];
#pragma unroll
      for (int r = 0; r < 4; ++r) at[r] = __shfl(alpha, quad * 4 + r, 64);
#pragma unroll
      for (int f = 0; f < 4; ++f)
#pragma unroll
        for (int r = 0; r < 4; ++r) o[f][r] *= at[r];
    }

    float psum = 0.f;
    short4_t pf[4];
#pragma unroll
    for (int s4 = 0; s4 < 4; ++s4) {
      float p0 = exp2_fast(s[s4 * 4 + 0] - m_i);
      float p1 = exp2_fast(s[s4 * 4 + 1] - m_i);
      float p2 = exp2_fast(s[s4 * 4 + 2] - m_i);
      float p3 = exp2_fast(s[s4 * 4 + 3] - m_i);
      psum += (p0 + p1) + (p2 + p3);
      unsigned lo, hi;
      asm("v_cvt_pk_bf16_f32 %0, %1, %2" : "=v"(lo) : "v"(p0), "v"(p1));
      asm("v_cvt_pk_bf16_f32 %0, %1, %2" : "=v"(hi) : "v"(p2), "v"(p3));
      uint2 packed;
      packed.x = lo;
      packed.y = hi;
      pf[s4] = __builtin_bit_cast(short4_t, packed);
    }
    psum += __shfl_xor(psum, 16, 64);
    psum += __shfl_xor(psum, 32, 64);
    l_i += psum;

#pragma unroll
    for (int f = 0; f < 4; ++f)
#pragma unroll
      for (int s4 = 0; s4 < 4; ++s4) {
        short4_t vf =
            *(const short4_t*)(lv + (f * 16 + lcol) * LDSPITCH + s4 * 16 + quad * 4);
        o[f] = __builtin_amdgcn_mfma_f32_16x16x16bf16_1k(pf[s4], vf, o[f], 0, 0, 0);
      }
  }

  float lt[4];
#pragma unroll
  for (int r = 0; r < 4; ++r) lt[r] = 1.f / __shfl(l_i, quad * 4 + r, 64);
#pragma unroll
  for (int f = 0; f < 4; ++f)
#pragma unroll
    for (int r = 0; r < 4; ++r) {
      int q = q0w + quad * 4 + r;
      int hd = f * 16 + lcol;
      ao[((size_t)b * Sq + q) * (NH * HD) + h * HD + hd] = f2bf(o[f][r] * lt[r]);
    }
}

extern "C" void kernel_launch(void* const* d_in, const int* in_sizes, int n_in,
                              void* d_out, int out_size, void* d_ws, size_t ws_size,
                              hipStream_t stream) {
  const float* x = (const float*)d_in[0];
  const float* Wq = (const float*)d_in[1];
  const float* Wk = (const float*)d_in[2];
  const float* Wv = (const float*)d_in[3];
  const float* Wo = (const float*)d_in[4];
  float* out = (float*)d_out;

  char* ws = (char*)d_ws;
  size_t off = 0;
  auto carve = [&](size_t bytes) {
    void* p = ws + off;
    off += (bytes + 255) & ~(size_t)255;
    return p;
  };
  const size_t xe = (size_t)Bz * Sq * Dm;
  const size_t we = (size_t)Dm * Dm;
  unsigned short* xb = (unsigned short*)carve(xe * 2);
  unsigned short* wqT = (unsigned short*)carve(we * 2);
  unsigned short* wkT = (unsigned short*)carve(we * 2);
  unsigned short* wvT = (unsigned short*)carve(we * 2);
  unsigned short* woT = (unsigned short*)carve(we * 2);
  unsigned short* qb = (unsigned short*)carve(xe * 2);
  unsigned short* kb = (unsigned short*)carve(xe * 2);
  unsigned short* vt = (unsigned short*)carve(xe * 2);
  unsigned short* ao = (unsigned short*)carve(xe * 2);
  (void)ws_size;

  cast_x_kernel<<<xe / 4 / 256, 256, 0, stream>>>(x, xb);
  transpose_w_kernel<<<dim3(16, 16, 4), 256, 0, stream>>>(Wq, Wk, Wv, Wo,
                                                          wqT, wkT, wvT, woT);
  gemm_qkv_kernel<<<dim3(8, 64, 3), 256, 0, stream>>>(xb, wqT, wkT, wvT, qb, kb, vt);
  attn_kernel<<<dim3(Bz * NH, 32), 256, 0, stream>>>(qb, kb, vt, ao);
  gemm_out_kernel<<<dim3(8, 64), 256, 0, stream>>>(ao, woT, out);
}

// Round 2
// 280.620 us; speedup vs baseline: 1.0489x; 1.0162x over previous
//
#include <hip/hip_runtime.h>

// SelfAttention: B=4 S=2048 D=1024 H=16 HD=64, causal, fp32 in/out, bf16 MFMA compute.
// R10->R11: attn LDS bank-conflict fix + more VALU diet.
// Counters R10: SQ_LDS_BANK_CONFLICT 1.3e7 (~23% of attn cycles), VALUBusy 59% vs
// MfmaUtil 24%. Changes:
// (1) K/V tiles staged via global_load_lds width=16 with PRE-SWIZZLED global source
//     (16B-granule XOR: granule ^= row&7), linear LDS dest, swizzled ds_read addrs
//     (rule: both-sides-or-neither). Pitch 72->64 shorts, LDS 18KB->16KB, and the
//     4x ds_write_b128 per thread per tile disappear (DMA direct to LDS).
// (2) 1/sqrt(HD)*log2(e) folded into Q at gemm_qkv epilogue -> no per-score mul in attn.
// (3) tmax via max3-friendly fmaxf tree (v_max3_f32), 15 -> 8 ops.
// Everything outside attn_kernel/gemm_qkv-epilogue identical to R10.

typedef __attribute__((ext_vector_type(8))) short short8_t;
typedef __attribute__((ext_vector_type(4))) short short4_t;
typedef __attribute__((ext_vector_type(4))) float float4_t;

constexpr int Bz = 4, Sq = 2048, Dm = 1024, NH = 16, HD = 64;

#define GLOAD_LDS16(g, l)                                                      \
  __builtin_amdgcn_global_load_lds(                                            \
      (const __attribute__((address_space(1))) unsigned int*)(g),              \
      (__attribute__((address_space(3))) unsigned int*)(l), 16, 0, 0)

__device__ __forceinline__ unsigned short f2bf(float f) {
  unsigned u = __builtin_bit_cast(unsigned, f);
  u += 0x7fffu + ((u >> 16) & 1u);
  return (unsigned short)(u >> 16);
}

__device__ __forceinline__ float exp2_fast(float x) {
#if __has_builtin(__builtin_amdgcn_exp2f)
  return __builtin_amdgcn_exp2f(x);
#else
  return exp2f(x);
#endif
}

__device__ __forceinline__ float m3(float a, float b, float c) {
  return fmaxf(fmaxf(a, b), c);  // clang emits v_max3_f32
}

__global__ __launch_bounds__(256) void cast_x_kernel(const float* __restrict__ x,
                                                     unsigned short* __restrict__ xb) {
  size_t i = (size_t)blockIdx.x * 256 + threadIdx.x;
  float4 v = ((const float4*)x)[i];
  ushort4 o;
  o.x = f2bf(v.x); o.y = f2bf(v.y); o.z = f2bf(v.z); o.w = f2bf(v.w);
  ((ushort4*)xb)[i] = o;
}

// All four W [K=1024][N=1024] fp32 -> WT [N][K] bf16 in one launch. grid (16,16,4).
__global__ __launch_bounds__(256) void transpose_w_kernel(
    const float* __restrict__ Wq, const float* __restrict__ Wk,
    const float* __restrict__ Wv, const float* __restrict__ Wo,
    unsigned short* __restrict__ wqT, unsigned short* __restrict__ wkT,
    unsigned short* __restrict__ wvT, unsigned short* __restrict__ woT) {
  __shared__ float tile[64][65];
  int zz = blockIdx.z;
  const float* W = zz == 0 ? Wq : (zz == 1 ? Wk : (zz == 2 ? Wv : Wo));
  unsigned short* WT = zz == 0 ? wqT : (zz == 1 ? wkT : (zz == 2 ? wvT : woT));
  int n0 = blockIdx.x * 64, k0 = blockIdx.y * 64;
  int tx = threadIdx.x & 63, ty = threadIdx.x >> 6;
#pragma unroll
  for (int i = 0; i < 16; ++i) {
    int r = i * 4 + ty;
    tile[r][tx] = W[(size_t)(k0 + r) * Dm + n0 + tx];
  }
  __syncthreads();
#pragma unroll
  for (int i = 0; i < 16; ++i) {
    int r = i * 4 + ty;
    WT[(size_t)(n0 + r) * Dm + k0 + tx] = f2bf(tile[tx][r]);
  }
}

// m97-style main loop: 128x128 tile, BK=64, glds width=16, unpadded LDS.
__device__ __forceinline__ void gemm_mainloop(const unsigned short* __restrict__ A,
                                              const unsigned short* __restrict__ BT,
                                              int m0, int n0,
                                              unsigned short* lA, unsigned short* lB,
                                              float4_t acc[4][4]) {
  const int tid = threadIdx.x;
  const int lane = tid & 63, lr = lane & 15, quad = lane >> 4;
  const int wave = tid >> 6;
  const int mw = (wave >> 1) * 64, nw = (wave & 1) * 64;
  const int srow = tid >> 3;
  const int scol = (tid & 7) * 8;
  const unsigned short* ga = A + (size_t)(m0 + srow) * Dm + scol;
  const unsigned short* gb = BT + (size_t)(n0 + srow) * Dm + scol;
  unsigned short* la = lA + tid * 8;
  unsigned short* lb = lB + tid * 8;

  for (int k0 = 0; k0 < Dm; k0 += 64) {
    __syncthreads();
#pragma unroll
    for (int iss = 0; iss < 4; ++iss) {
      GLOAD_LDS16(ga + (size_t)iss * 32 * Dm + k0, la + iss * 32 * 64);
      GLOAD_LDS16(gb + (size_t)iss * 32 * Dm + k0, lb + iss * 32 * 64);
    }
    __syncthreads();
#pragma unroll
    for (int kk = 0; kk < 2; ++kk) {
      short8_t a[4], b[4];
#pragma unroll
      for (int i = 0; i < 4; ++i)
        a[i] = *(const short8_t*)(lA + (mw + i * 16 + lr) * 64 + kk * 32 + quad * 8);
#pragma unroll
      for (int j = 0; j < 4; ++j)
        b[j] = *(const short8_t*)(lB + (nw + j * 16 + lr) * 64 + kk * 32 + quad * 8);
#pragma unroll
      for (int i = 0; i < 4; ++i)
#pragma unroll
        for (int j = 0; j < 4; ++j)
          acc[i][j] = __builtin_amdgcn_mfma_f32_16x16x32_bf16(a[i], b[j], acc[i][j], 0, 0, 0);
    }
  }
}

// QKV projections. Q,K -> [B,H,S,HD]; V -> TRANSPOSED [B,H,HD,S]. grid (8,64,3)
// Q output is pre-scaled by 0.125*log2(e) so attn scores land in log2 domain for free.
__global__ __launch_bounds__(256) void gemm_qkv_kernel(
    const unsigned short* __restrict__ xb,
    const unsigned short* __restrict__ wqT, const unsigned short* __restrict__ wkT,
    const unsigned short* __restrict__ wvT,
    unsigned short* __restrict__ qb, unsigned short* __restrict__ kb,
    unsigned short* __restrict__ vt) {
  __shared__ unsigned short lA[128 * 64];
  __shared__ unsigned short lB[128 * 64];
  const unsigned short* WT = blockIdx.z == 0 ? wqT : (blockIdx.z == 1 ? wkT : wvT);
  unsigned short* outb = blockIdx.z == 0 ? qb : (blockIdx.z == 1 ? kb : vt);
  bool isV = blockIdx.z == 2;
  float qscale = (blockIdx.z == 0) ? 0.18033688011112042f : 1.0f;
  int lane = threadIdx.x & 63, wave = threadIdx.x >> 6;
  int lr = lane & 15, quad = lane >> 4;
  int m0 = blockIdx.y * 128, n0 = blockIdx.x * 128;
  int m_base = m0 + (wave >> 1) * 64;
  int n_base = n0 + (wave & 1) * 64;
  float4_t z = {0.f, 0.f, 0.f, 0.f};
  float4_t acc[4][4];
#pragma unroll
  for (int i = 0; i < 4; ++i)
#pragma unroll
    for (int j = 0; j < 4; ++j) acc[i][j] = z;
  gemm_mainloop(xb, WT, m0, n0, lA, lB, acc);
  if (isV) {
#pragma unroll
    for (int i = 0; i < 4; ++i)
#pragma unroll
      for (int j = 0; j < 4; ++j) {
        int m = m_base + i * 16 + quad * 4;
        int n = n_base + j * 16 + lr;
        int b = m >> 11, s = m & (Sq - 1);
        int h = n >> 6, hd = n & (HD - 1);
        ushort4 pk;
        pk.x = f2bf(acc[i][j][0]); pk.y = f2bf(acc[i][j][1]);
        pk.z = f2bf(acc[i][j][2]); pk.w = f2bf(acc[i][j][3]);
        *(ushort4*)(outb + (((size_t)b * NH + h) * HD + hd) * Sq + s) = pk;
      }
  } else {
#pragma unroll
    for (int i = 0; i < 4; ++i)
#pragma unroll
      for (int j = 0; j < 4; ++j)
#pragma unroll
        for (int r = 0; r < 4; ++r) {
          int m = m_base + i * 16 + quad * 4 + r;
          int n = n_base + j * 16 + lr;
          int b = m >> 11, s = m & (Sq - 1);
          int h = n >> 6, hd = n & (HD - 1);
          outb[(((size_t)b * NH + h) * Sq + s) * HD + hd] = f2bf(acc[i][j][r] * qscale);
        }
  }
}

// Output projection: ao_bf16 [8192,1024] @ Wo -> fp32 out. grid (8,64)
__global__ __launch_bounds__(256) void gemm_out_kernel(
    const unsigned short* __restrict__ ao, const unsigned short* __restrict__ woT,
    float* __restrict__ out) {
  __shared__ unsigned short lA[128 * 64];
  __shared__ unsigned short lB[128 * 64];
  int lane = threadIdx.x & 63, wave = threadIdx.x >> 6;
  int lr = lane & 15, quad = lane >> 4;
  int m0 = blockIdx.y * 128, n0 = blockIdx.x * 128;
  int m_base = m0 + (wave >> 1) * 64;
  int n_base = n0 + (wave & 1) * 64;
  float4_t z = {0.f, 0.f, 0.f, 0.f};
  float4_t acc[4][4];
#pragma unroll
  for (int i = 0; i < 4; ++i)
#pragma unroll
    for (int j = 0; j < 4; ++j) acc[i][j] = z;
  gemm_mainloop(ao, woT, m0, n0, lA, lB, acc);
#pragma unroll
  for (int i = 0; i < 4; ++i)
#pragma unroll
    for (int j = 0; j < 4; ++j)
#pragma unroll
      for (int r = 0; r < 4; ++r) {
        int m = m_base + i * 16 + quad * 4 + r;
        int n = n_base + j * 16 + lr;
        out[(size_t)m * Dm + n] = acc[i][j][r];
      }
}

// Flash attention — grid (B*H, 32), one 64-row q-tile per block, ti = 31 - blockIdx.y.
// K/V LDS tiles: pitch 64 shorts, 16B-granule XOR swizzle (granule ^= row&7),
// staged by global_load_lds width=16 with pre-swizzled global source.
__global__ __launch_bounds__(256) void attn_kernel(
    const unsigned short* __restrict__ qbuf, const unsigned short* __restrict__ kbuf,
    const unsigned short* __restrict__ vtbuf, unsigned short* __restrict__ ao) {
  __shared__ unsigned short lk[64 * 64];
  __shared__ unsigned short lv[64 * 64];
  int tid = threadIdx.x;
  int bh = blockIdx.x;
  int ti = 31 - (int)blockIdx.y;
  int wave = tid >> 6, lane = tid & 63;
  int lcol = lane & 15, quad = lane >> 4;
  int lc7 = lcol & 7;
  const unsigned short* Q = qbuf + (size_t)bh * Sq * HD;
  const unsigned short* K = kbuf + (size_t)bh * Sq * HD;
  const unsigned short* Vt = vtbuf + (size_t)bh * HD * Sq;
  int b = bh >> 4, h = bh & 15;
  float4_t z = {0.f, 0.f, 0.f, 0.f};

  // Staging map: granule G = call*256 + tid; row r = G>>3 (call1: +32), gi = G&7.
  // Source granule = gi ^ (r&7) (involution), dest linear -> read with same XOR.
  const int r0 = tid >> 3;                     // 0..31
  const int sg = (tid & 7) ^ (r0 & 7);         // pre-swizzled source granule
  const unsigned short* kg_base = K + (size_t)r0 * HD + sg * 8;
  const unsigned short* vg_base = Vt + (size_t)r0 * Sq + sg * 8;
  unsigned short* kl0 = lk + tid * 8;
  unsigned short* kl1 = lk + 2048 + tid * 8;
  unsigned short* vl0 = lv + tid * 8;
  unsigned short* vl1 = lv + 2048 + tid * 8;

  // Swizzled read offsets (shorts). QK row granules {quad, quad|4}; PV granule
  // u = s4*2 + (quad>>1), sub-offset (quad&1)*4. row&7 == lcol&7 for all rows used.
  const int koff0 = (quad ^ lc7) * 8;
  const int koff1 = ((quad | 4) ^ lc7) * 8;
  int voff[4];
#pragma unroll
  for (int s4 = 0; s4 < 4; ++s4)
    voff[s4] = (((s4 * 2 + (quad >> 1)) ^ lc7) * 8) + (quad & 1) * 4;

  int q0w = ti * 64 + wave * 16;
  int q_global = q0w + lcol;
  short8_t qf0 = *(const short8_t*)(Q + (size_t)(q0w + lcol) * HD + quad * 8);
  short8_t qf1 = *(const short8_t*)(Q + (size_t)(q0w + lcol) * HD + 32 + quad * 8);
  float m_i = -INFINITY, l_i = 0.f;
  float4_t o[4];
#pragma unroll
  for (int f = 0; f < 4; ++f) o[f] = z;

  int nkt = ti + 1;
  for (int kt = 0; kt < nkt; ++kt) {
    int key0 = kt * 64;
    __syncthreads();
    {
      const unsigned short* kg = kg_base + (size_t)key0 * HD;
      const unsigned short* vg = vg_base + key0;
      GLOAD_LDS16(kg, kl0);
      GLOAD_LDS16(kg + (size_t)32 * HD, kl1);
      GLOAD_LDS16(vg, vl0);
      GLOAD_LDS16(vg + (size_t)32 * Sq, vl1);
    }
    __syncthreads();

    bool need_mask = (key0 + 63 > q0w);
    float s[16];
#pragma unroll
    for (int s4 = 0; s4 < 4; ++s4) {
      const unsigned short* kr = lk + (s4 * 16 + lcol) * 64;
      short8_t kf0 = *(const short8_t*)(kr + koff0);
      short8_t kf1 = *(const short8_t*)(kr + koff1);
      float4_t st = z;
      st = __builtin_amdgcn_mfma_f32_16x16x32_bf16(kf0, qf0, st, 0, 0, 0);
      st = __builtin_amdgcn_mfma_f32_16x16x32_bf16(kf1, qf1, st, 0, 0, 0);
#pragma unroll
      for (int r = 0; r < 4; ++r) {
        float v = st[r];  // already log2-domain: Q pre-scaled by 0.125*log2e
        if (need_mask && (key0 + s4 * 16 + quad * 4 + r > q_global)) v = -INFINITY;
        s[s4 * 4 + r] = v;
      }
    }
    // max3-tree reduction over 16 values
    float ta = m3(s[0], s[1], s[2]);
    float tb = m3(s[3], s[4], s[5]);
    float tc = m3(s[6], s[7], s[8]);
    float td = m3(s[9], s[10], s[11]);
    float te = m3(s[12], s[13], s[14]);
    float tmax = m3(ta, tb, tc);
    tmax = m3(tmax, td, te);
    tmax = fmaxf(tmax, s[15]);
    tmax = fmaxf(tmax, __shfl_xor(tmax, 16, 64));
    tmax = fmaxf(tmax, __shfl_xor(tmax, 32, 64));

    // T13 defer-max: only rescale when the running max actually grew by >8
    // (log2 domain => P bounded by 2^8 = 256; f32 psum and bf16 P are safe).
    if (__any(tmax > m_i + 8.f)) {
      float m_new = fmaxf(m_i, tmax);
      float alpha = exp2_fast(m_i - m_new);
      l_i *= alpha;
      m_i = m_new;
      float at[4];
#pragma unroll
      for (int r = 0; r < 4; ++r) at[r] = __shfl(alpha, quad * 4 + r, 64);
#pragma unroll
      for (int f = 0; f < 4; ++f)
#pragma unroll
        for (int r = 0; r < 4; ++r) o[f][r] *= at[r];
    }

    float psum = 0.f;
    short4_t pf[4];
#pragma unroll
    for (int s4 = 0; s4 < 4; ++s4) {
      float p0 = exp2_fast(s[s4 * 4 + 0] - m_i);
      float p1 = exp2_fast(s[s4 * 4 + 1] - m_i);
      float p2 = exp2_fast(s[s4 * 4 + 2] - m_i);
      float p3 = exp2_fast(s[s4 * 4 + 3] - m_i);
      psum += (p0 + p1) + (p2 + p3);
      unsigned lo, hi;
      asm("v_cvt_pk_bf16_f32 %0, %1, %2" : "=v"(lo) : "v"(p0), "v"(p1));
      asm("v_cvt_pk_bf16_f32 %0, %1, %2" : "=v"(hi) : "v"(p2), "v"(p3));
      uint2 packed;
      packed.x = lo;
      packed.y = hi;
      pf[s4] = __builtin_bit_cast(short4_t, packed);
    }
    psum += __shfl_xor(psum, 16, 64);
    psum += __shfl_xor(psum, 32, 64);
    l_i += psum;

#pragma unroll
    for (int f = 0; f < 4; ++f) {
      const unsigned short* vr = lv + (f * 16 + lcol) * 64;
#pragma unroll
      for (int s4 = 0; s4 < 4; ++s4) {
        short4_t vf = *(const short4_t*)(vr + voff[s4]);
        o[f] = __builtin_amdgcn_mfma_f32_16x16x16bf16_1k(pf[s4], vf, o[f], 0, 0, 0);
      }
    }
  }

  float lt[4];
#pragma unroll
  for (int r = 0; r < 4; ++r) lt[r] = 1.f / __shfl(l_i, quad * 4 + r, 64);
#pragma unroll
  for (int f = 0; f < 4; ++f)
#pragma unroll
    for (int r = 0; r < 4; ++r) {
      int q = q0w + quad * 4 + r;
      int hd = f * 16 + lcol;
      ao[((size_t)b * Sq + q) * (NH * HD) + h * HD + hd] = f2bf(o[f][r] * lt[r]);
    }
}

extern "C" void kernel_launch(void* const* d_in, const int* in_sizes, int n_in,
                              void* d_out, int out_size, void* d_ws, size_t ws_size,
                              hipStream_t stream) {
  const float* x = (const float*)d_in[0];
  const float* Wq = (const float*)d_in[1];
  const float* Wk = (const float*)d_in[2];
  const float* Wv = (const float*)d_in[3];
  const float* Wo = (const float*)d_in[4];
  float* out = (float*)d_out;

  char* ws = (char*)d_ws;
  size_t off = 0;
  auto carve = [&](size_t bytes) {
    void* p = ws + off;
    off += (bytes + 255) & ~(size_t)255;
    return p;
  };
  const size_t xe = (size_t)Bz * Sq * Dm;
  const size_t we = (size_t)Dm * Dm;
  unsigned short* xb = (unsigned short*)carve(xe * 2);
  unsigned short* wqT = (unsigned short*)carve(we * 2);
  unsigned short* wkT = (unsigned short*)carve(we * 2);
  unsigned short* wvT = (unsigned short*)carve(we * 2);
  unsigned short* woT = (unsigned short*)carve(we * 2);
  unsigned short* qb = (unsigned short*)carve(xe * 2);
  unsigned short* kb = (unsigned short*)carve(xe * 2);
  unsigned short* vt = (unsigned short*)carve(xe * 2);
  unsigned short* ao = (unsigned short*)carve(xe * 2);
  (void)ws_size;

  cast_x_kernel<<<xe / 4 / 256, 256, 0, stream>>>(x, xb);
  transpose_w_kernel<<<dim3(16, 16, 4), 256, 0, stream>>>(Wq, Wk, Wv, Wo,
                                                          wqT, wkT, wvT, woT);
  gemm_qkv_kernel<<<dim3(8, 64, 3), 256, 0, stream>>>(xb, wqT, wkT, wvT, qb, kb, vt);
  attn_kernel<<<dim3(Bz * NH, 32), 256, 0, stream>>>(qb, kb, vt, ao);
  gemm_out_kernel<<<dim3(8, 64), 256, 0, stream>>>(ao, woT, out);
}

// Round 3
// 270.368 us; speedup vs baseline: 1.0887x; 1.0379x over previous
//
#include <hip/hip_runtime.h>

// SelfAttention: B=4 S=2048 D=1024 H=16 HD=64, causal, fp32 in/out, bf16 MFMA compute.
// R11->R12: attn double-buffered pipeline + 8B-granular V swizzle.
// R11 counters: conflicts 8.65e6 (residual = PV ds_read_b64: 16B-granule XOR can't
// spread the 8B half-slot -> half banks idle, 2x serialization), occupancy 35%,
// per-tile serial load latency (no dbuf). Changes:
// (1) K/V double-buffered, ONE barrier/tile: next-tile V global->regs + K glds->alt
//     buffer issued before compute; V ds_writes (auto vmcnt wait) land after QK,
//     hidden under softmax; PV; barrier. Load latency overlaps ~600cyc compute.
// (2) V now reg-staged with 8B-slot swizzle slot^=(row&15): PV reads become
//     conflict-free ((s4*4+quad)^lcol is a bijection over 16 slots per phase).
//     K stays global_load_lds + 16B-granule swizzle (QK b128 reads are at floor).
// (3) Causal mask applied only on the diagonal tile (uniform kt==ti branch).
// gemm/cast/transpose kernels unchanged from R11.

typedef __attribute__((ext_vector_type(8))) short short8_t;
typedef __attribute__((ext_vector_type(4))) short short4_t;
typedef __attribute__((ext_vector_type(4))) float float4_t;

constexpr int Bz = 4, Sq = 2048, Dm = 1024, NH = 16, HD = 64;

#define GLOAD_LDS16(g, l)                                                      \
  __builtin_amdgcn_global_load_lds(                                            \
      (const __attribute__((address_space(1))) unsigned int*)(g),              \
      (__attribute__((address_space(3))) unsigned int*)(l), 16, 0, 0)

__device__ __forceinline__ unsigned short f2bf(float f) {
  unsigned u = __builtin_bit_cast(unsigned, f);
  u += 0x7fffu + ((u >> 16) & 1u);
  return (unsigned short)(u >> 16);
}

__device__ __forceinline__ float exp2_fast(float x) {
#if __has_builtin(__builtin_amdgcn_exp2f)
  return __builtin_amdgcn_exp2f(x);
#else
  return exp2f(x);
#endif
}

__device__ __forceinline__ float m3(float a, float b, float c) {
  return fmaxf(fmaxf(a, b), c);  // clang emits v_max3_f32
}

__global__ __launch_bounds__(256) void cast_x_kernel(const float* __restrict__ x,
                                                     unsigned short* __restrict__ xb) {
  size_t i = (size_t)blockIdx.x * 256 + threadIdx.x;
  float4 v = ((const float4*)x)[i];
  ushort4 o;
  o.x = f2bf(v.x); o.y = f2bf(v.y); o.z = f2bf(v.z); o.w = f2bf(v.w);
  ((ushort4*)xb)[i] = o;
}

// All four W [K=1024][N=1024] fp32 -> WT [N][K] bf16 in one launch. grid (16,16,4).
__global__ __launch_bounds__(256) void transpose_w_kernel(
    const float* __restrict__ Wq, const float* __restrict__ Wk,
    const float* __restrict__ Wv, const float* __restrict__ Wo,
    unsigned short* __restrict__ wqT, unsigned short* __restrict__ wkT,
    unsigned short* __restrict__ wvT, unsigned short* __restrict__ woT) {
  __shared__ float tile[64][65];
  int zz = blockIdx.z;
  const float* W = zz == 0 ? Wq : (zz == 1 ? Wk : (zz == 2 ? Wv : Wo));
  unsigned short* WT = zz == 0 ? wqT : (zz == 1 ? wkT : (zz == 2 ? wvT : woT));
  int n0 = blockIdx.x * 64, k0 = blockIdx.y * 64;
  int tx = threadIdx.x & 63, ty = threadIdx.x >> 6;
#pragma unroll
  for (int i = 0; i < 16; ++i) {
    int r = i * 4 + ty;
    tile[r][tx] = W[(size_t)(k0 + r) * Dm + n0 + tx];
  }
  __syncthreads();
#pragma unroll
  for (int i = 0; i < 16; ++i) {
    int r = i * 4 + ty;
    WT[(size_t)(n0 + r) * Dm + k0 + tx] = f2bf(tile[tx][r]);
  }
}

// m97-style main loop: 128x128 tile, BK=64, glds width=16, unpadded LDS.
__device__ __forceinline__ void gemm_mainloop(const unsigned short* __restrict__ A,
                                              const unsigned short* __restrict__ BT,
                                              int m0, int n0,
                                              unsigned short* lA, unsigned short* lB,
                                              float4_t acc[4][4]) {
  const int tid = threadIdx.x;
  const int lane = tid & 63, lr = lane & 15, quad = lane >> 4;
  const int wave = tid >> 6;
  const int mw = (wave >> 1) * 64, nw = (wave & 1) * 64;
  const int srow = tid >> 3;
  const int scol = (tid & 7) * 8;
  const unsigned short* ga = A + (size_t)(m0 + srow) * Dm + scol;
  const unsigned short* gb = BT + (size_t)(n0 + srow) * Dm + scol;
  unsigned short* la = lA + tid * 8;
  unsigned short* lb = lB + tid * 8;

  for (int k0 = 0; k0 < Dm; k0 += 64) {
    __syncthreads();
#pragma unroll
    for (int iss = 0; iss < 4; ++iss) {
      GLOAD_LDS16(ga + (size_t)iss * 32 * Dm + k0, la + iss * 32 * 64);
      GLOAD_LDS16(gb + (size_t)iss * 32 * Dm + k0, lb + iss * 32 * 64);
    }
    __syncthreads();
#pragma unroll
    for (int kk = 0; kk < 2; ++kk) {
      short8_t a[4], b[4];
#pragma unroll
      for (int i = 0; i < 4; ++i)
        a[i] = *(const short8_t*)(lA + (mw + i * 16 + lr) * 64 + kk * 32 + quad * 8);
#pragma unroll
      for (int j = 0; j < 4; ++j)
        b[j] = *(const short8_t*)(lB + (nw + j * 16 + lr) * 64 + kk * 32 + quad * 8);
#pragma unroll
      for (int i = 0; i < 4; ++i)
#pragma unroll
        for (int j = 0; j < 4; ++j)
          acc[i][j] = __builtin_amdgcn_mfma_f32_16x16x32_bf16(a[i], b[j], acc[i][j], 0, 0, 0);
    }
  }
}

// QKV projections. Q,K -> [B,H,S,HD]; V -> TRANSPOSED [B,H,HD,S]. grid (8,64,3)
// Q output is pre-scaled by 0.125*log2(e) so attn scores land in log2 domain for free.
__global__ __launch_bounds__(256) void gemm_qkv_kernel(
    const unsigned short* __restrict__ xb,
    const unsigned short* __restrict__ wqT, const unsigned short* __restrict__ wkT,
    const unsigned short* __restrict__ wvT,
    unsigned short* __restrict__ qb, unsigned short* __restrict__ kb,
    unsigned short* __restrict__ vt) {
  __shared__ unsigned short lA[128 * 64];
  __shared__ unsigned short lB[128 * 64];
  const unsigned short* WT = blockIdx.z == 0 ? wqT : (blockIdx.z == 1 ? wkT : wvT);
  unsigned short* outb = blockIdx.z == 0 ? qb : (blockIdx.z == 1 ? kb : vt);
  bool isV = blockIdx.z == 2;
  float qscale = (blockIdx.z == 0) ? 0.18033688011112042f : 1.0f;
  int lane = threadIdx.x & 63, wave = threadIdx.x >> 6;
  int lr = lane & 15, quad = lane >> 4;
  int m0 = blockIdx.y * 128, n0 = blockIdx.x * 128;
  int m_base = m0 + (wave >> 1) * 64;
  int n_base = n0 + (wave & 1) * 64;
  float4_t z = {0.f, 0.f, 0.f, 0.f};
  float4_t acc[4][4];
#pragma unroll
  for (int i = 0; i < 4; ++i)
#pragma unroll
    for (int j = 0; j < 4; ++j) acc[i][j] = z;
  gemm_mainloop(xb, WT, m0, n0, lA, lB, acc);
  if (isV) {
#pragma unroll
    for (int i = 0; i < 4; ++i)
#pragma unroll
      for (int j = 0; j < 4; ++j) {
        int m = m_base + i * 16 + quad * 4;
        int n = n_base + j * 16 + lr;
        int b = m >> 11, s = m & (Sq - 1);
        int h = n >> 6, hd = n & (HD - 1);
        ushort4 pk;
        pk.x = f2bf(acc[i][j][0]); pk.y = f2bf(acc[i][j][1]);
        pk.z = f2bf(acc[i][j][2]); pk.w = f2bf(acc[i][j][3]);
        *(ushort4*)(outb + (((size_t)b * NH + h) * HD + hd) * Sq + s) = pk;
      }
  } else {
#pragma unroll
    for (int i = 0; i < 4; ++i)
#pragma unroll
      for (int j = 0; j < 4; ++j)
#pragma unroll
        for (int r = 0; r < 4; ++r) {
          int m = m_base + i * 16 + quad * 4 + r;
          int n = n_base + j * 16 + lr;
          int b = m >> 11, s = m & (Sq - 1);
          int h = n >> 6, hd = n & (HD - 1);
          outb[(((size_t)b * NH + h) * Sq + s) * HD + hd] = f2bf(acc[i][j][r] * qscale);
        }
  }
}

// Output projection: ao_bf16 [8192,1024] @ Wo -> fp32 out. grid (8,64)
__global__ __launch_bounds__(256) void gemm_out_kernel(
    const unsigned short* __restrict__ ao, const unsigned short* __restrict__ woT,
    float* __restrict__ out) {
  __shared__ unsigned short lA[128 * 64];
  __shared__ unsigned short lB[128 * 64];
  int lane = threadIdx.x & 63, wave = threadIdx.x >> 6;
  int lr = lane & 15, quad = lane >> 4;
  int m0 = blockIdx.y * 128, n0 = blockIdx.x * 128;
  int m_base = m0 + (wave >> 1) * 64;
  int n_base = n0 + (wave & 1) * 64;
  float4_t z = {0.f, 0.f, 0.f, 0.f};
  float4_t acc[4][4];
#pragma unroll
  for (int i = 0; i < 4; ++i)
#pragma unroll
    for (int j = 0; j < 4; ++j) acc[i][j] = z;
  gemm_mainloop(ao, woT, m0, n0, lA, lB, acc);
#pragma unroll
  for (int i = 0; i < 4; ++i)
#pragma unroll
    for (int j = 0; j < 4; ++j)
#pragma unroll
      for (int r = 0; r < 4; ++r) {
        int m = m_base + i * 16 + quad * 4 + r;
        int n = n_base + j * 16 + lr;
        out[(size_t)m * Dm + n] = acc[i][j][r];
      }
}

// Flash attention — grid (B*H, 32), one 64-row q-tile per block, ti = 31 - blockIdx.y.
// Double-buffered K (glds, 16B-granule XOR) and V (reg-staged, 8B-slot XOR ^row&15).
__global__ __launch_bounds__(256) void attn_kernel(
    const unsigned short* __restrict__ qbuf, const unsigned short* __restrict__ kbuf,
    const unsigned short* __restrict__ vtbuf, unsigned short* __restrict__ ao) {
  __shared__ unsigned short lk[2 * 64 * 64];
  __shared__ unsigned short lv[2 * 64 * 64];
  int tid = threadIdx.x;
  int bh = blockIdx.x;
  int ti = 31 - (int)blockIdx.y;
  int wave = tid >> 6, lane = tid & 63;
  int lcol = lane & 15, quad = lane >> 4;
  int lc7 = lcol & 7;
  const unsigned short* Q = qbuf + (size_t)bh * Sq * HD;
  const unsigned short* K = kbuf + (size_t)bh * Sq * HD;
  const unsigned short* Vt = vtbuf + (size_t)bh * HD * Sq;
  int b = bh >> 4, h = bh & 15;
  float4_t z = {0.f, 0.f, 0.f, 0.f};

  // --- K staging map (glds direct, 16B granule g ^= row&7) ---
  const int r0 = tid >> 3;                    // 0..31 (second call: +32)
  const int sgk = (tid & 7) ^ (r0 & 7);       // pre-swizzled source granule
  const unsigned short* kg = K + (size_t)r0 * HD + sgk * 8;  // += 64*HD per tile
  const int kdst = tid * 8;                   // linear dest (shorts)

  // --- V staging map (reg-staged, 8B slot d = w ^ (row&15)) ---
  // Thread owns content slots w0,w0+1 of rows r0 and r0+32 (same row&15).
  const int w0 = (tid & 7) * 2;
  const int xa = r0 & 15;
  const int d0 = w0 ^ xa;                     // LDS slot holding content slot w0
  const unsigned short* vsrc = Vt + (size_t)r0 * Sq + w0 * 4;  // += 64 per tile
  const int vdst = r0 * 64 + d0 * 4;          // shorts; partner slot = vdst ^ 4

  // --- swizzled read offsets ---
  const int koff0 = (quad ^ lc7) * 8;
  const int koff1 = ((quad | 4) ^ lc7) * 8;
  int voff[4];
#pragma unroll
  for (int s4 = 0; s4 < 4; ++s4) voff[s4] = ((s4 * 4 + quad) ^ lcol) * 4;

  unsigned short* lkc = lk;
  unsigned short* lkn = lk + 4096;
  unsigned short* lvc = lv;
  unsigned short* lvn = lv + 4096;

  int q0w = ti * 64 + wave * 16;
  int q_global = q0w + lcol;
  short8_t qf0 = *(const short8_t*)(Q + (size_t)(q0w + lcol) * HD + quad * 8);
  short8_t qf1 = *(const short8_t*)(Q + (size_t)(q0w + lcol) * HD + 32 + quad * 8);
  float m_i = -INFINITY, l_i = 0.f;
  float4_t o[4];
#pragma unroll
  for (int f = 0; f < 4; ++f) o[f] = z;

  // --- prologue: stage tile 0 into current buffers ---
  {
    GLOAD_LDS16(kg, lkc + kdst);
    GLOAD_LDS16(kg + (size_t)32 * HD, lkc + 2048 + kdst);
    short4_t a0 = *(const short4_t*)(vsrc);
    short4_t a1 = *(const short4_t*)(vsrc + 4);
    short4_t b0 = *(const short4_t*)(vsrc + (size_t)32 * Sq);
    short4_t b1 = *(const short4_t*)(vsrc + (size_t)32 * Sq + 4);
    *(short4_t*)(lvc + vdst) = a0;
    *(short4_t*)(lvc + (vdst ^ 4)) = a1;
    *(short4_t*)(lvc + vdst + 2048) = b0;
    *(short4_t*)(lvc + (vdst ^ 4) + 2048) = b1;
  }
  __syncthreads();

  int nkt = ti + 1;
  for (int kt = 0; kt < nkt; ++kt) {
    bool has_next = (kt + 1 < nkt);
    short4_t a0, a1, b0, b1;
    if (has_next) {
      // issue next-tile V loads first (reg dep waits at vmcnt(2), hidden under QK)
      const unsigned short* vs = vsrc + (size_t)(kt + 1) * 64;
      a0 = *(const short4_t*)(vs);
      a1 = *(const short4_t*)(vs + 4);
      b0 = *(const short4_t*)(vs + (size_t)32 * Sq);
      b1 = *(const short4_t*)(vs + (size_t)32 * Sq + 4);
      // then K glds into the alternate buffer (drained by the end-of-iter barrier)
      const unsigned short* kgn = kg + (size_t)(kt + 1) * 64 * HD;
      GLOAD_LDS16(kgn, lkn + kdst);
      GLOAD_LDS16(kgn + (size_t)32 * HD, lkn + 2048 + kdst);
    }

    // --- QK^T from lkc ---
    float s[16];
#pragma unroll
    for (int s4 = 0; s4 < 4; ++s4) {
      const unsigned short* kr = lkc + (s4 * 16 + lcol) * 64;
      short8_t kf0 = *(const short8_t*)(kr + koff0);
      short8_t kf1 = *(const short8_t*)(kr + koff1);
      float4_t st = z;
      st = __builtin_amdgcn_mfma_f32_16x16x32_bf16(kf0, qf0, st, 0, 0, 0);
      st = __builtin_amdgcn_mfma_f32_16x16x32_bf16(kf1, qf1, st, 0, 0, 0);
#pragma unroll
      for (int r = 0; r < 4; ++r) s[s4 * 4 + r] = st[r];
    }
    if (kt == ti) {  // diagonal tile: causal mask (uniform branch)
      int key0 = kt * 64;
#pragma unroll
      for (int s4 = 0; s4 < 4; ++s4)
#pragma unroll
        for (int r = 0; r < 4; ++r)
          if (key0 + s4 * 16 + quad * 4 + r > q_global) s[s4 * 4 + r] = -INFINITY;
    }

    // max3-tree reduction over 16 values
    float ta = m3(s[0], s[1], s[2]);
    float tb = m3(s[3], s[4], s[5]);
    float tc = m3(s[6], s[7], s[8]);
    float td = m3(s[9], s[10], s[11]);
    float te = m3(s[12], s[13], s[14]);
    float tmax = m3(ta, tb, tc);
    tmax = m3(tmax, td, te);
    tmax = fmaxf(tmax, s[15]);
    tmax = fmaxf(tmax, __shfl_xor(tmax, 16, 64));
    tmax = fmaxf(tmax, __shfl_xor(tmax, 32, 64));

    // T13 defer-max (log2 domain, THR=8 -> P bounded by 256)
    if (__any(tmax > m_i + 8.f)) {
      float m_new = fmaxf(m_i, tmax);
      float alpha = exp2_fast(m_i - m_new);
      l_i *= alpha;
      m_i = m_new;
      float at[4];
#pragma unroll
      for (int r = 0; r < 4; ++r) at[r] = __shfl(alpha, quad * 4 + r, 64);
#pragma unroll
      for (int f = 0; f < 4; ++f)
#pragma unroll
        for (int r = 0; r < 4; ++r) o[f][r] *= at[r];
    }

    float psum = 0.f;
    short4_t pf[4];
#pragma unroll
    for (int s4 = 0; s4 < 4; ++s4) {
      float p0 = exp2_fast(s[s4 * 4 + 0] - m_i);
      float p1 = exp2_fast(s[s4 * 4 + 1] - m_i);
      float p2 = exp2_fast(s[s4 * 4 + 2] - m_i);
      float p3 = exp2_fast(s[s4 * 4 + 3] - m_i);
      psum += (p0 + p1) + (p2 + p3);
      unsigned lo, hi;
      asm("v_cvt_pk_bf16_f32 %0, %1, %2" : "=v"(lo) : "v"(p0), "v"(p1));
      asm("v_cvt_pk_bf16_f32 %0, %1, %2" : "=v"(hi) : "v"(p2), "v"(p3));
      uint2 packed;
      packed.x = lo;
      packed.y = hi;
      pf[s4] = __builtin_bit_cast(short4_t, packed);
    }
    psum += __shfl_xor(psum, 16, 64);
    psum += __shfl_xor(psum, 32, 64);
    l_i += psum;

    // --- write next-tile V into alternate buffer (vmcnt wait was hidden above) ---
    if (has_next) {
      *(short4_t*)(lvn + vdst) = a0;
      *(short4_t*)(lvn + (vdst ^ 4)) = a1;
      *(short4_t*)(lvn + vdst + 2048) = b0;
      *(short4_t*)(lvn + (vdst ^ 4) + 2048) = b1;
    }

    // --- PV from lvc (conflict-free swizzled b64 reads) ---
#pragma unroll
    for (int f = 0; f < 4; ++f) {
      const unsigned short* vr = lvc + (f * 16 + lcol) * 64;
#pragma unroll
      for (int s4 = 0; s4 < 4; ++s4) {
        short4_t vf = *(const short4_t*)(vr + voff[s4]);
        o[f] = __builtin_amdgcn_mfma_f32_16x16x16bf16_1k(pf[s4], vf, o[f], 0, 0, 0);
      }
    }

    __syncthreads();  // drains K glds (vmcnt0) + V ds_writes; buffers swap
    unsigned short* t;
    t = lkc; lkc = lkn; lkn = t;
    t = lvc; lvc = lvn; lvn = t;
  }

  float lt[4];
#pragma unroll
  for (int r = 0; r < 4; ++r) lt[r] = 1.f / __shfl(l_i, quad * 4 + r, 64);
#pragma unroll
  for (int f = 0; f < 4; ++f)
#pragma unroll
    for (int r = 0; r < 4; ++r) {
      int q = q0w + quad * 4 + r;
      int hd = f * 16 + lcol;
      ao[((size_t)b * Sq + q) * (NH * HD) + h * HD + hd] = f2bf(o[f][r] * lt[r]);
    }
}

extern "C" void kernel_launch(void* const* d_in, const int* in_sizes, int n_in,
                              void* d_out, int out_size, void* d_ws, size_t ws_size,
                              hipStream_t stream) {
  const float* x = (const float*)d_in[0];
  const float* Wq = (const float*)d_in[1];
  const float* Wk = (const float*)d_in[2];
  const float* Wv = (const float*)d_in[3];
  const float* Wo = (const float*)d_in[4];
  float* out = (float*)d_out;

  char* ws = (char*)d_ws;
  size_t off = 0;
  auto carve = [&](size_t bytes) {
    void* p = ws + off;
    off += (bytes + 255) & ~(size_t)255;
    return p;
  };
  const size_t xe = (size_t)Bz * Sq * Dm;
  const size_t we = (size_t)Dm * Dm;
  unsigned short* xb = (unsigned short*)carve(xe * 2);
  unsigned short* wqT = (unsigned short*)carve(we * 2);
  unsigned short* wkT = (unsigned short*)carve(we * 2);
  unsigned short* wvT = (unsigned short*)carve(we * 2);
  unsigned short* woT = (unsigned short*)carve(we * 2);
  unsigned short* qb = (unsigned short*)carve(xe * 2);
  unsigned short* kb = (unsigned short*)carve(xe * 2);
  unsigned short* vt = (unsigned short*)carve(xe * 2);
  unsigned short* ao = (unsigned short*)carve(xe * 2);
  (void)ws_size;

  cast_x_kernel<<<xe / 4 / 256, 256, 0, stream>>>(x, xb);
  transpose_w_kernel<<<dim3(16, 16, 4), 256, 0, stream>>>(Wq, Wk, Wv, Wo,
                                                          wqT, wkT, wvT, woT);
  gemm_qkv_kernel<<<dim3(8, 64, 3), 256, 0, stream>>>(xb, wqT, wkT, wvT, qb, kb, vt);
  attn_kernel<<<dim3(Bz * NH, 32), 256, 0, stream>>>(qb, kb, vt, ao);
  gemm_out_kernel<<<dim3(8, 64), 256, 0, stream>>>(ao, woT, out);
}

// Round 4
// 266.979 us; speedup vs baseline: 1.1025x; 1.0127x over previous
//
#include <hip/hip_runtime.h>

// SelfAttention: B=4 S=2048 D=1024 H=16 HD=64, causal, fp32 in/out, bf16 MFMA compute.
// R12->R13: XCD-aware block swizzle (T1) on both GEMM kernels.
// R12 counters: gemm_qkv is now #1 (88us): MfmaUtil 23.5 / VALUBusy 17.7 / occ 19.7
// (latency-bound), FETCH_SIZE 200MB vs ~54MB ideal = 12x A-panel over-fetch.
// Cause: grid (8,64,3) x-fastest => the 8 blocks sharing an A-slice round-robin
// across 8 XCDs, so every XCD re-fetches every A slice from HBM and the K-step
// barrier drain eats HBM-miss (~900cy) instead of L2-hit (~200cy) latency.
// Fix: bijective swizzle logical=(lin%8)*cpx+lin/8 (nwg%8==0: qkv cpx=192, out
// cpx=64) => consecutive logical tiles (same A-slice) land on one XCD; W panels
// (2MB/z) stay L2-resident. attn grid already XCD-local (sharers at stride 64).
// attn/cast/transpose byte-identical to R12.

typedef __attribute__((ext_vector_type(8))) short short8_t;
typedef __attribute__((ext_vector_type(4))) short short4_t;
typedef __attribute__((ext_vector_type(4))) float float4_t;

constexpr int Bz = 4, Sq = 2048, Dm = 1024, NH = 16, HD = 64;

#define GLOAD_LDS16(g, l)                                                      \
  __builtin_amdgcn_global_load_lds(                                            \
      (const __attribute__((address_space(1))) unsigned int*)(g),              \
      (__attribute__((address_space(3))) unsigned int*)(l), 16, 0, 0)

__device__ __forceinline__ unsigned short f2bf(float f) {
  unsigned u = __builtin_bit_cast(unsigned, f);
  u += 0x7fffu + ((u >> 16) & 1u);
  return (unsigned short)(u >> 16);
}

__device__ __forceinline__ float exp2_fast(float x) {
#if __has_builtin(__builtin_amdgcn_exp2f)
  return __builtin_amdgcn_exp2f(x);
#else
  return exp2f(x);
#endif
}

__device__ __forceinline__ float m3(float a, float b, float c) {
  return fmaxf(fmaxf(a, b), c);  // clang emits v_max3_f32
}

__global__ __launch_bounds__(256) void cast_x_kernel(const float* __restrict__ x,
                                                     unsigned short* __restrict__ xb) {
  size_t i = (size_t)blockIdx.x * 256 + threadIdx.x;
  float4 v = ((const float4*)x)[i];
  ushort4 o;
  o.x = f2bf(v.x); o.y = f2bf(v.y); o.z = f2bf(v.z); o.w = f2bf(v.w);
  ((ushort4*)xb)[i] = o;
}

// All four W [K=1024][N=1024] fp32 -> WT [N][K] bf16 in one launch. grid (16,16,4).
__global__ __launch_bounds__(256) void transpose_w_kernel(
    const float* __restrict__ Wq, const float* __restrict__ Wk,
    const float* __restrict__ Wv, const float* __restrict__ Wo,
    unsigned short* __restrict__ wqT, unsigned short* __restrict__ wkT,
    unsigned short* __restrict__ wvT, unsigned short* __restrict__ woT) {
  __shared__ float tile[64][65];
  int zz = blockIdx.z;
  const float* W = zz == 0 ? Wq : (zz == 1 ? Wk : (zz == 2 ? Wv : Wo));
  unsigned short* WT = zz == 0 ? wqT : (zz == 1 ? wkT : (zz == 2 ? wvT : woT));
  int n0 = blockIdx.x * 64, k0 = blockIdx.y * 64;
  int tx = threadIdx.x & 63, ty = threadIdx.x >> 6;
#pragma unroll
  for (int i = 0; i < 16; ++i) {
    int r = i * 4 + ty;
    tile[r][tx] = W[(size_t)(k0 + r) * Dm + n0 + tx];
  }
  __syncthreads();
#pragma unroll
  for (int i = 0; i < 16; ++i) {
    int r = i * 4 + ty;
    WT[(size_t)(n0 + r) * Dm + k0 + tx] = f2bf(tile[tx][r]);
  }
}

// m97-style main loop: 128x128 tile, BK=64, glds width=16, unpadded LDS.
__device__ __forceinline__ void gemm_mainloop(const unsigned short* __restrict__ A,
                                              const unsigned short* __restrict__ BT,
                                              int m0, int n0,
                                              unsigned short* lA, unsigned short* lB,
                                              float4_t acc[4][4]) {
  const int tid = threadIdx.x;
  const int lane = tid & 63, lr = lane & 15, quad = lane >> 4;
  const int wave = tid >> 6;
  const int mw = (wave >> 1) * 64, nw = (wave & 1) * 64;
  const int srow = tid >> 3;
  const int scol = (tid & 7) * 8;
  const unsigned short* ga = A + (size_t)(m0 + srow) * Dm + scol;
  const unsigned short* gb = BT + (size_t)(n0 + srow) * Dm + scol;
  unsigned short* la = lA + tid * 8;
  unsigned short* lb = lB + tid * 8;

  for (int k0 = 0; k0 < Dm; k0 += 64) {
    __syncthreads();
#pragma unroll
    for (int iss = 0; iss < 4; ++iss) {
      GLOAD_LDS16(ga + (size_t)iss * 32 * Dm + k0, la + iss * 32 * 64);
      GLOAD_LDS16(gb + (size_t)iss * 32 * Dm + k0, lb + iss * 32 * 64);
    }
    __syncthreads();
#pragma unroll
    for (int kk = 0; kk < 2; ++kk) {
      short8_t a[4], b[4];
#pragma unroll
      for (int i = 0; i < 4; ++i)
        a[i] = *(const short8_t*)(lA + (mw + i * 16 + lr) * 64 + kk * 32 + quad * 8);
#pragma unroll
      for (int j = 0; j < 4; ++j)
        b[j] = *(const short8_t*)(lB + (nw + j * 16 + lr) * 64 + kk * 32 + quad * 8);
#pragma unroll
      for (int i = 0; i < 4; ++i)
#pragma unroll
        for (int j = 0; j < 4; ++j)
          acc[i][j] = __builtin_amdgcn_mfma_f32_16x16x32_bf16(a[i], b[j], acc[i][j], 0, 0, 0);
    }
  }
}

// QKV projections. Q,K -> [B,H,S,HD]; V -> TRANSPOSED [B,H,HD,S]. grid (8,64,3)
// XCD-swizzled: logical=(lin%8)*192+lin/8 so A-slice sharers co-locate on one XCD.
// Q output is pre-scaled by 0.125*log2(e) so attn scores land in log2 domain for free.
__global__ __launch_bounds__(256) void gemm_qkv_kernel(
    const unsigned short* __restrict__ xb,
    const unsigned short* __restrict__ wqT, const unsigned short* __restrict__ wkT,
    const unsigned short* __restrict__ wvT,
    unsigned short* __restrict__ qb, unsigned short* __restrict__ kb,
    unsigned short* __restrict__ vt) {
  __shared__ unsigned short lA[128 * 64];
  __shared__ unsigned short lB[128 * 64];
  // T1 XCD swizzle: nwg=1536, cpx=192
  int lin = (int)blockIdx.x + 8 * ((int)blockIdx.y + 64 * (int)blockIdx.z);
  int logical = (lin & 7) * 192 + (lin >> 3);
  int bx = logical & 7;
  int rest = logical >> 3;
  int by = rest & 63;
  int bz = rest >> 6;
  const unsigned short* WT = bz == 0 ? wqT : (bz == 1 ? wkT : wvT);
  unsigned short* outb = bz == 0 ? qb : (bz == 1 ? kb : vt);
  bool isV = bz == 2;
  float qscale = (bz == 0) ? 0.18033688011112042f : 1.0f;
  int lane = threadIdx.x & 63, wave = threadIdx.x >> 6;
  int lr = lane & 15, quad = lane >> 4;
  int m0 = by * 128, n0 = bx * 128;
  int m_base = m0 + (wave >> 1) * 64;
  int n_base = n0 + (wave & 1) * 64;
  float4_t z = {0.f, 0.f, 0.f, 0.f};
  float4_t acc[4][4];
#pragma unroll
  for (int i = 0; i < 4; ++i)
#pragma unroll
    for (int j = 0; j < 4; ++j) acc[i][j] = z;
  gemm_mainloop(xb, WT, m0, n0, lA, lB, acc);
  if (isV) {
#pragma unroll
    for (int i = 0; i < 4; ++i)
#pragma unroll
      for (int j = 0; j < 4; ++j) {
        int m = m_base + i * 16 + quad * 4;
        int n = n_base + j * 16 + lr;
        int b = m >> 11, s = m & (Sq - 1);
        int h = n >> 6, hd = n & (HD - 1);
        ushort4 pk;
        pk.x = f2bf(acc[i][j][0]); pk.y = f2bf(acc[i][j][1]);
        pk.z = f2bf(acc[i][j][2]); pk.w = f2bf(acc[i][j][3]);
        *(ushort4*)(outb + (((size_t)b * NH + h) * HD + hd) * Sq + s) = pk;
      }
  } else {
#pragma unroll
    for (int i = 0; i < 4; ++i)
#pragma unroll
      for (int j = 0; j < 4; ++j)
#pragma unroll
        for (int r = 0; r < 4; ++r) {
          int m = m_base + i * 16 + quad * 4 + r;
          int n = n_base + j * 16 + lr;
          int b = m >> 11, s = m & (Sq - 1);
          int h = n >> 6, hd = n & (HD - 1);
          outb[(((size_t)b * NH + h) * Sq + s) * HD + hd] = f2bf(acc[i][j][r] * qscale);
        }
  }
}

// Output projection: ao_bf16 [8192,1024] @ Wo -> fp32 out. grid (8,64), XCD-swizzled.
__global__ __launch_bounds__(256) void gemm_out_kernel(
    const unsigned short* __restrict__ ao, const unsigned short* __restrict__ woT,
    float* __restrict__ out) {
  __shared__ unsigned short lA[128 * 64];
  __shared__ unsigned short lB[128 * 64];
  // T1 XCD swizzle: nwg=512, cpx=64
  int lin = (int)blockIdx.x + 8 * (int)blockIdx.y;
  int logical = (lin & 7) * 64 + (lin >> 3);
  int bx = logical & 7;
  int by = logical >> 3;
  int lane = threadIdx.x & 63, wave = threadIdx.x >> 6;
  int lr = lane & 15, quad = lane >> 4;
  int m0 = by * 128, n0 = bx * 128;
  int m_base = m0 + (wave >> 1) * 64;
  int n_base = n0 + (wave & 1) * 64;
  float4_t z = {0.f, 0.f, 0.f, 0.f};
  float4_t acc[4][4];
#pragma unroll
  for (int i = 0; i < 4; ++i)
#pragma unroll
    for (int j = 0; j < 4; ++j) acc[i][j] = z;
  gemm_mainloop(ao, woT, m0, n0, lA, lB, acc);
#pragma unroll
  for (int i = 0; i < 4; ++i)
#pragma unroll
    for (int j = 0; j < 4; ++j)
#pragma unroll
      for (int r = 0; r < 4; ++r) {
        int m = m_base + i * 16 + quad * 4 + r;
        int n = n_base + j * 16 + lr;
        out[(size_t)m * Dm + n] = acc[i][j][r];
      }
}

// Flash attention — grid (B*H, 32), one 64-row q-tile per block, ti = 31 - blockIdx.y.
// Double-buffered K (glds, 16B-granule XOR) and V (reg-staged, 8B-slot XOR ^row&15).
__global__ __launch_bounds__(256) void attn_kernel(
    const unsigned short* __restrict__ qbuf, const unsigned short* __restrict__ kbuf,
    const unsigned short* __restrict__ vtbuf, unsigned short* __restrict__ ao) {
  __shared__ unsigned short lk[2 * 64 * 64];
  __shared__ unsigned short lv[2 * 64 * 64];
  int tid = threadIdx.x;
  int bh = blockIdx.x;
  int ti = 31 - (int)blockIdx.y;
  int wave = tid >> 6, lane = tid & 63;
  int lcol = lane & 15, quad = lane >> 4;
  int lc7 = lcol & 7;
  const unsigned short* Q = qbuf + (size_t)bh * Sq * HD;
  const unsigned short* K = kbuf + (size_t)bh * Sq * HD;
  const unsigned short* Vt = vtbuf + (size_t)bh * HD * Sq;
  int b = bh >> 4, h = bh & 15;
  float4_t z = {0.f, 0.f, 0.f, 0.f};

  // --- K staging map (glds direct, 16B granule g ^= row&7) ---
  const int r0 = tid >> 3;                    // 0..31 (second call: +32)
  const int sgk = (tid & 7) ^ (r0 & 7);       // pre-swizzled source granule
  const unsigned short* kg = K + (size_t)r0 * HD + sgk * 8;  // += 64*HD per tile
  const int kdst = tid * 8;                   // linear dest (shorts)

  // --- V staging map (reg-staged, 8B slot d = w ^ (row&15)) ---
  const int w0 = (tid & 7) * 2;
  const int xa = r0 & 15;
  const int d0 = w0 ^ xa;                     // LDS slot holding content slot w0
  const unsigned short* vsrc = Vt + (size_t)r0 * Sq + w0 * 4;  // += 64 per tile
  const int vdst = r0 * 64 + d0 * 4;          // shorts; partner slot = vdst ^ 4

  // --- swizzled read offsets ---
  const int koff0 = (quad ^ lc7) * 8;
  const int koff1 = ((quad | 4) ^ lc7) * 8;
  int voff[4];
#pragma unroll
  for (int s4 = 0; s4 < 4; ++s4) voff[s4] = ((s4 * 4 + quad) ^ lcol) * 4;

  unsigned short* lkc = lk;
  unsigned short* lkn = lk + 4096;
  unsigned short* lvc = lv;
  unsigned short* lvn = lv + 4096;

  int q0w = ti * 64 + wave * 16;
  int q_global = q0w + lcol;
  short8_t qf0 = *(const short8_t*)(Q + (size_t)(q0w + lcol) * HD + quad * 8);
  short8_t qf1 = *(const short8_t*)(Q + (size_t)(q0w + lcol) * HD + 32 + quad * 8);
  float m_i = -INFINITY, l_i = 0.f;
  float4_t o[4];
#pragma unroll
  for (int f = 0; f < 4; ++f) o[f] = z;

  // --- prologue: stage tile 0 into current buffers ---
  {
    GLOAD_LDS16(kg, lkc + kdst);
    GLOAD_LDS16(kg + (size_t)32 * HD, lkc + 2048 + kdst);
    short4_t a0 = *(const short4_t*)(vsrc);
    short4_t a1 = *(const short4_t*)(vsrc + 4);
    short4_t b0 = *(const short4_t*)(vsrc + (size_t)32 * Sq);
    short4_t b1 = *(const short4_t*)(vsrc + (size_t)32 * Sq + 4);
    *(short4_t*)(lvc + vdst) = a0;
    *(short4_t*)(lvc + (vdst ^ 4)) = a1;
    *(short4_t*)(lvc + vdst + 2048) = b0;
    *(short4_t*)(lvc + (vdst ^ 4) + 2048) = b1;
  }
  __syncthreads();

  int nkt = ti + 1;
  for (int kt = 0; kt < nkt; ++kt) {
    bool has_next = (kt + 1 < nkt);
    short4_t a0, a1, b0, b1;
    if (has_next) {
      const unsigned short* vs = vsrc + (size_t)(kt + 1) * 64;
      a0 = *(const short4_t*)(vs);
      a1 = *(const short4_t*)(vs + 4);
      b0 = *(const short4_t*)(vs + (size_t)32 * Sq);
      b1 = *(const short4_t*)(vs + (size_t)32 * Sq + 4);
      const unsigned short* kgn = kg + (size_t)(kt + 1) * 64 * HD;
      GLOAD_LDS16(kgn, lkn + kdst);
      GLOAD_LDS16(kgn + (size_t)32 * HD, lkn + 2048 + kdst);
    }

    // --- QK^T from lkc ---
    float s[16];
#pragma unroll
    for (int s4 = 0; s4 < 4; ++s4) {
      const unsigned short* kr = lkc + (s4 * 16 + lcol) * 64;
      short8_t kf0 = *(const short8_t*)(kr + koff0);
      short8_t kf1 = *(const short8_t*)(kr + koff1);
      float4_t st = z;
      st = __builtin_amdgcn_mfma_f32_16x16x32_bf16(kf0, qf0, st, 0, 0, 0);
      st = __builtin_amdgcn_mfma_f32_16x16x32_bf16(kf1, qf1, st, 0, 0, 0);
#pragma unroll
      for (int r = 0; r < 4; ++r) s[s4 * 4 + r] = st[r];
    }
    if (kt == ti) {  // diagonal tile: causal mask (uniform branch)
      int key0 = kt * 64;
#pragma unroll
      for (int s4 = 0; s4 < 4; ++s4)
#pragma unroll
        for (int r = 0; r < 4; ++r)
          if (key0 + s4 * 16 + quad * 4 + r > q_global) s[s4 * 4 + r] = -INFINITY;
    }

    // max3-tree reduction over 16 values
    float ta = m3(s[0], s[1], s[2]);
    float tb = m3(s[3], s[4], s[5]);
    float tc = m3(s[6], s[7], s[8]);
    float td = m3(s[9], s[10], s[11]);
    float te = m3(s[12], s[13], s[14]);
    float tmax = m3(ta, tb, tc);
    tmax = m3(tmax, td, te);
    tmax = fmaxf(tmax, s[15]);
    tmax = fmaxf(tmax, __shfl_xor(tmax, 16, 64));
    tmax = fmaxf(tmax, __shfl_xor(tmax, 32, 64));

    // T13 defer-max (log2 domain, THR=8 -> P bounded by 256)
    if (__any(tmax > m_i + 8.f)) {
      float m_new = fmaxf(m_i, tmax);
      float alpha = exp2_fast(m_i - m_new);
      l_i *= alpha;
      m_i = m_new;
      float at[4];
#pragma unroll
      for (int r = 0; r < 4; ++r) at[r] = __shfl(alpha, quad * 4 + r, 64);
#pragma unroll
      for (int f = 0; f < 4; ++f)
#pragma unroll
        for (int r = 0; r < 4; ++r) o[f][r] *= at[r];
    }

    float psum = 0.f;
    short4_t pf[4];
#pragma unroll
    for (int s4 = 0; s4 < 4; ++s4) {
      float p0 = exp2_fast(s[s4 * 4 + 0] - m_i);
      float p1 = exp2_fast(s[s4 * 4 + 1] - m_i);
      float p2 = exp2_fast(s[s4 * 4 + 2] - m_i);
      float p3 = exp2_fast(s[s4 * 4 + 3] - m_i);
      psum += (p0 + p1) + (p2 + p3);
      unsigned lo, hi;
      asm("v_cvt_pk_bf16_f32 %0, %1, %2" : "=v"(lo) : "v"(p0), "v"(p1));
      asm("v_cvt_pk_bf16_f32 %0, %1, %2" : "=v"(hi) : "v"(p2), "v"(p3));
      uint2 packed;
      packed.x = lo;
      packed.y = hi;
      pf[s4] = __builtin_bit_cast(short4_t, packed);
    }
    psum += __shfl_xor(psum, 16, 64);
    psum += __shfl_xor(psum, 32, 64);
    l_i += psum;

    // --- write next-tile V into alternate buffer (vmcnt wait was hidden above) ---
    if (has_next) {
      *(short4_t*)(lvn + vdst) = a0;
      *(short4_t*)(lvn + (vdst ^ 4)) = a1;
      *(short4_t*)(lvn + vdst + 2048) = b0;
      *(short4_t*)(lvn + (vdst ^ 4) + 2048) = b1;
    }

    // --- PV from lvc (conflict-free swizzled b64 reads) ---
#pragma unroll
    for (int f = 0; f < 4; ++f) {
      const unsigned short* vr = lvc + (f * 16 + lcol) * 64;
#pragma unroll
      for (int s4 = 0; s4 < 4; ++s4) {
        short4_t vf = *(const short4_t*)(vr + voff[s4]);
        o[f] = __builtin_amdgcn_mfma_f32_16x16x16bf16_1k(pf[s4], vf, o[f], 0, 0, 0);
      }
    }

    __syncthreads();  // drains K glds (vmcnt0) + V ds_writes; buffers swap
    unsigned short* t;
    t = lkc; lkc = lkn; lkn = t;
    t = lvc; lvc = lvn; lvn = t;
  }

  float lt[4];
#pragma unroll
  for (int r = 0; r < 4; ++r) lt[r] = 1.f / __shfl(l_i, quad * 4 + r, 64);
#pragma unroll
  for (int f = 0; f < 4; ++f)
#pragma unroll
    for (int r = 0; r < 4; ++r) {
      int q = q0w + quad * 4 + r;
      int hd = f * 16 + lcol;
      ao[((size_t)b * Sq + q) * (NH * HD) + h * HD + hd] = f2bf(o[f][r] * lt[r]);
    }
}

extern "C" void kernel_launch(void* const* d_in, const int* in_sizes, int n_in,
                              void* d_out, int out_size, void* d_ws, size_t ws_size,
                              hipStream_t stream) {
  const float* x = (const float*)d_in[0];
  const float* Wq = (const float*)d_in[1];
  const float* Wk = (const float*)d_in[2];
  const float* Wv = (const float*)d_in[3];
  const float* Wo = (const float*)d_in[4];
  float* out = (float*)d_out;

  char* ws = (char*)d_ws;
  size_t off = 0;
  auto carve = [&](size_t bytes) {
    void* p = ws + off;
    off += (bytes + 255) & ~(size_t)255;
    return p;
  };
  const size_t xe = (size_t)Bz * Sq * Dm;
  const size_t we = (size_t)Dm * Dm;
  unsigned short* xb = (unsigned short*)carve(xe * 2);
  unsigned short* wqT = (unsigned short*)carve(we * 2);
  unsigned short* wkT = (unsigned short*)carve(we * 2);
  unsigned short* wvT = (unsigned short*)carve(we * 2);
  unsigned short* woT = (unsigned short*)carve(we * 2);
  unsigned short* qb = (unsigned short*)carve(xe * 2);
  unsigned short* kb = (unsigned short*)carve(xe * 2);
  unsigned short* vt = (unsigned short*)carve(xe * 2);
  unsigned short* ao = (unsigned short*)carve(xe * 2);
  (void)ws_size;

  cast_x_kernel<<<xe / 4 / 256, 256, 0, stream>>>(x, xb);
  transpose_w_kernel<<<dim3(16, 16, 4), 256, 0, stream>>>(Wq, Wk, Wv, Wo,
                                                          wqT, wkT, wvT, woT);
  gemm_qkv_kernel<<<dim3(8, 64, 3), 256, 0, stream>>>(xb, wqT, wkT, wvT, qb, kb, vt);
  attn_kernel<<<dim3(Bz * NH, 32), 256, 0, stream>>>(qb, kb, vt, ao);
  gemm_out_kernel<<<dim3(8, 64), 256, 0, stream>>>(ao, woT, out);
}

// Round 5
// 258.609 us; speedup vs baseline: 1.1382x; 1.0324x over previous
//
#include <hip/hip_runtime.h>

// SelfAttention: B=4 S=2048 D=1024 H=16 HD=64, causal, fp32 in/out, bf16 MFMA compute.
// R13->R14: GEMM mainloop 2-phase prefetch pipeline (T3-minimum recipe).
// R13 counters: gemm_qkv 89us, MfmaUtil 22.6 / VALUBusy 16.9 / occ 18.5, FETCH at
// ideal 49MB -> structural latency: old loop was barrier->stage->barrier(vmcnt0
// drain)->compute, so every K-step exposes the full L2 service time (~1000cy/CU)
// with all waves synchronized at the same boundary and nothing to overlap it.
// Fix (same transformation as R12's attn dbuf): LDS double-buffer; per K-step
// issue next-tile glds into alt buffer FIRST, compute current, then ONE
// __syncthreads() whose vmcnt(0) drain waits on loads issued ~500cy earlier.
// LDS 32->64KB (2 blocks/CU; qkv grid = 3 exact rounds, out grid = 1 exact).
// attn/cast/transpose byte-identical to R13.

typedef __attribute__((ext_vector_type(8))) short short8_t;
typedef __attribute__((ext_vector_type(4))) short short4_t;
typedef __attribute__((ext_vector_type(4))) float float4_t;

constexpr int Bz = 4, Sq = 2048, Dm = 1024, NH = 16, HD = 64;

#define GLOAD_LDS16(g, l)                                                      \
  __builtin_amdgcn_global_load_lds(                                            \
      (const __attribute__((address_space(1))) unsigned int*)(g),              \
      (__attribute__((address_space(3))) unsigned int*)(l), 16, 0, 0)

__device__ __forceinline__ unsigned short f2bf(float f) {
  unsigned u = __builtin_bit_cast(unsigned, f);
  u += 0x7fffu + ((u >> 16) & 1u);
  return (unsigned short)(u >> 16);
}

__device__ __forceinline__ float exp2_fast(float x) {
#if __has_builtin(__builtin_amdgcn_exp2f)
  return __builtin_amdgcn_exp2f(x);
#else
  return exp2f(x);
#endif
}

__device__ __forceinline__ float m3(float a, float b, float c) {
  return fmaxf(fmaxf(a, b), c);  // clang emits v_max3_f32
}

__global__ __launch_bounds__(256) void cast_x_kernel(const float* __restrict__ x,
                                                     unsigned short* __restrict__ xb) {
  size_t i = (size_t)blockIdx.x * 256 + threadIdx.x;
  float4 v = ((const float4*)x)[i];
  ushort4 o;
  o.x = f2bf(v.x); o.y = f2bf(v.y); o.z = f2bf(v.z); o.w = f2bf(v.w);
  ((ushort4*)xb)[i] = o;
}

// All four W [K=1024][N=1024] fp32 -> WT [N][K] bf16 in one launch. grid (16,16,4).
__global__ __launch_bounds__(256) void transpose_w_kernel(
    const float* __restrict__ Wq, const float* __restrict__ Wk,
    const float* __restrict__ Wv, const float* __restrict__ Wo,
    unsigned short* __restrict__ wqT, unsigned short* __restrict__ wkT,
    unsigned short* __restrict__ wvT, unsigned short* __restrict__ woT) {
  __shared__ float tile[64][65];
  int zz = blockIdx.z;
  const float* W = zz == 0 ? Wq : (zz == 1 ? Wk : (zz == 2 ? Wv : Wo));
  unsigned short* WT = zz == 0 ? wqT : (zz == 1 ? wkT : (zz == 2 ? wvT : woT));
  int n0 = blockIdx.x * 64, k0 = blockIdx.y * 64;
  int tx = threadIdx.x & 63, ty = threadIdx.x >> 6;
#pragma unroll
  for (int i = 0; i < 16; ++i) {
    int r = i * 4 + ty;
    tile[r][tx] = W[(size_t)(k0 + r) * Dm + n0 + tx];
  }
  __syncthreads();
#pragma unroll
  for (int i = 0; i < 16; ++i) {
    int r = i * 4 + ty;
    WT[(size_t)(n0 + r) * Dm + k0 + tx] = f2bf(tile[tx][r]);
  }
}

// 2-phase prefetch mainloop: 128x128 tile, BK=64, glds width=16, LDS double-buffered.
// lA/lB each hold TWO 128x64 tiles (2*8192 shorts).
__device__ __forceinline__ void gemm_mainloop(const unsigned short* __restrict__ A,
                                              const unsigned short* __restrict__ BT,
                                              int m0, int n0,
                                              unsigned short* lA, unsigned short* lB,
                                              float4_t acc[4][4]) {
  const int tid = threadIdx.x;
  const int lane = tid & 63, lr = lane & 15, quad = lane >> 4;
  const int wave = tid >> 6;
  const int mw = (wave >> 1) * 64, nw = (wave & 1) * 64;
  const int srow = tid >> 3;
  const int scol = (tid & 7) * 8;
  const unsigned short* ga = A + (size_t)(m0 + srow) * Dm + scol;
  const unsigned short* gb = BT + (size_t)(n0 + srow) * Dm + scol;

  // prologue: stage K-step 0 into buffer 0
#pragma unroll
  for (int iss = 0; iss < 4; ++iss) {
    GLOAD_LDS16(ga + (size_t)iss * 32 * Dm, lA + tid * 8 + iss * 32 * 64);
    GLOAD_LDS16(gb + (size_t)iss * 32 * Dm, lB + tid * 8 + iss * 32 * 64);
  }
  __syncthreads();

  int cur = 0;
  for (int k0 = 0; k0 < Dm; k0 += 64) {
    const unsigned short* cA = lA + cur * 8192;
    const unsigned short* cB = lB + cur * 8192;
    if (k0 + 64 < Dm) {
      // issue next K-step's loads into the alternate buffer FIRST
      unsigned short* nA = lA + (cur ^ 1) * 8192;
      unsigned short* nB = lB + (cur ^ 1) * 8192;
#pragma unroll
      for (int iss = 0; iss < 4; ++iss) {
        GLOAD_LDS16(ga + (size_t)iss * 32 * Dm + k0 + 64, nA + tid * 8 + iss * 32 * 64);
        GLOAD_LDS16(gb + (size_t)iss * 32 * Dm + k0 + 64, nB + tid * 8 + iss * 32 * 64);
      }
    }
#pragma unroll
    for (int kk = 0; kk < 2; ++kk) {
      short8_t a[4], b[4];
#pragma unroll
      for (int i = 0; i < 4; ++i)
        a[i] = *(const short8_t*)(cA + (mw + i * 16 + lr) * 64 + kk * 32 + quad * 8);
#pragma unroll
      for (int j = 0; j < 4; ++j)
        b[j] = *(const short8_t*)(cB + (nw + j * 16 + lr) * 64 + kk * 32 + quad * 8);
#pragma unroll
      for (int i = 0; i < 4; ++i)
#pragma unroll
        for (int j = 0; j < 4; ++j)
          acc[i][j] = __builtin_amdgcn_mfma_f32_16x16x32_bf16(a[i], b[j], acc[i][j], 0, 0, 0);
    }
    __syncthreads();  // drains next-tile glds (issued ~500cy ago) + protects reuse
    cur ^= 1;
  }
}

// QKV projections. Q,K -> [B,H,S,HD]; V -> TRANSPOSED [B,H,HD,S]. grid (8,64,3)
// XCD-swizzled: logical=(lin%8)*192+lin/8 so A-slice sharers co-locate on one XCD.
// Q output is pre-scaled by 0.125*log2(e) so attn scores land in log2 domain for free.
__global__ __launch_bounds__(256) void gemm_qkv_kernel(
    const unsigned short* __restrict__ xb,
    const unsigned short* __restrict__ wqT, const unsigned short* __restrict__ wkT,
    const unsigned short* __restrict__ wvT,
    unsigned short* __restrict__ qb, unsigned short* __restrict__ kb,
    unsigned short* __restrict__ vt) {
  __shared__ unsigned short lA[2 * 128 * 64];
  __shared__ unsigned short lB[2 * 128 * 64];
  // T1 XCD swizzle: nwg=1536, cpx=192
  int lin = (int)blockIdx.x + 8 * ((int)blockIdx.y + 64 * (int)blockIdx.z);
  int logical = (lin & 7) * 192 + (lin >> 3);
  int bx = logical & 7;
  int rest = logical >> 3;
  int by = rest & 63;
  int bz = rest >> 6;
  const unsigned short* WT = bz == 0 ? wqT : (bz == 1 ? wkT : wvT);
  unsigned short* outb = bz == 0 ? qb : (bz == 1 ? kb : vt);
  bool isV = bz == 2;
  float qscale = (bz == 0) ? 0.18033688011112042f : 1.0f;
  int lane = threadIdx.x & 63, wave = threadIdx.x >> 6;
  int lr = lane & 15, quad = lane >> 4;
  int m0 = by * 128, n0 = bx * 128;
  int m_base = m0 + (wave >> 1) * 64;
  int n_base = n0 + (wave & 1) * 64;
  float4_t z = {0.f, 0.f, 0.f, 0.f};
  float4_t acc[4][4];
#pragma unroll
  for (int i = 0; i < 4; ++i)
#pragma unroll
    for (int j = 0; j < 4; ++j) acc[i][j] = z;
  gemm_mainloop(xb, WT, m0, n0, lA, lB, acc);
  if (isV) {
#pragma unroll
    for (int i = 0; i < 4; ++i)
#pragma unroll
      for (int j = 0; j < 4; ++j) {
        int m = m_base + i * 16 + quad * 4;
        int n = n_base + j * 16 + lr;
        int b = m >> 11, s = m & (Sq - 1);
        int h = n >> 6, hd = n & (HD - 1);
        ushort4 pk;
        pk.x = f2bf(acc[i][j][0]); pk.y = f2bf(acc[i][j][1]);
        pk.z = f2bf(acc[i][j][2]); pk.w = f2bf(acc[i][j][3]);
        *(ushort4*)(outb + (((size_t)b * NH + h) * HD + hd) * Sq + s) = pk;
      }
  } else {
#pragma unroll
    for (int i = 0; i < 4; ++i)
#pragma unroll
      for (int j = 0; j < 4; ++j)
#pragma unroll
        for (int r = 0; r < 4; ++r) {
          int m = m_base + i * 16 + quad * 4 + r;
          int n = n_base + j * 16 + lr;
          int b = m >> 11, s = m & (Sq - 1);
          int h = n >> 6, hd = n & (HD - 1);
          outb[(((size_t)b * NH + h) * Sq + s) * HD + hd] = f2bf(acc[i][j][r] * qscale);
        }
  }
}

// Output projection: ao_bf16 [8192,1024] @ Wo -> fp32 out. grid (8,64), XCD-swizzled.
__global__ __launch_bounds__(256) void gemm_out_kernel(
    const unsigned short* __restrict__ ao, const unsigned short* __restrict__ woT,
    float* __restrict__ out) {
  __shared__ unsigned short lA[2 * 128 * 64];
  __shared__ unsigned short lB[2 * 128 * 64];
  // T1 XCD swizzle: nwg=512, cpx=64
  int lin = (int)blockIdx.x + 8 * (int)blockIdx.y;
  int logical = (lin & 7) * 64 + (lin >> 3);
  int bx = logical & 7;
  int by = logical >> 3;
  int lane = threadIdx.x & 63, wave = threadIdx.x >> 6;
  int lr = lane & 15, quad = lane >> 4;
  int m0 = by * 128, n0 = bx * 128;
  int m_base = m0 + (wave >> 1) * 64;
  int n_base = n0 + (wave & 1) * 64;
  float4_t z = {0.f, 0.f, 0.f, 0.f};
  float4_t acc[4][4];
#pragma unroll
  for (int i = 0; i < 4; ++i)
#pragma unroll
    for (int j = 0; j < 4; ++j) acc[i][j] = z;
  gemm_mainloop(ao, woT, m0, n0, lA, lB, acc);
#pragma unroll
  for (int i = 0; i < 4; ++i)
#pragma unroll
    for (int j = 0; j < 4; ++j)
#pragma unroll
      for (int r = 0; r < 4; ++r) {
        int m = m_base + i * 16 + quad * 4 + r;
        int n = n_base + j * 16 + lr;
        out[(size_t)m * Dm + n] = acc[i][j][r];
      }
}

// Flash attention — grid (B*H, 32), one 64-row q-tile per block, ti = 31 - blockIdx.y.
// Double-buffered K (glds, 16B-granule XOR) and V (reg-staged, 8B-slot XOR ^row&15).
__global__ __launch_bounds__(256) void attn_kernel(
    const unsigned short* __restrict__ qbuf, const unsigned short* __restrict__ kbuf,
    const unsigned short* __restrict__ vtbuf, unsigned short* __restrict__ ao) {
  __shared__ unsigned short lk[2 * 64 * 64];
  __shared__ unsigned short lv[2 * 64 * 64];
  int tid = threadIdx.x;
  int bh = blockIdx.x;
  int ti = 31 - (int)blockIdx.y;
  int wave = tid >> 6, lane = tid & 63;
  int lcol = lane & 15, quad = lane >> 4;
  int lc7 = lcol & 7;
  const unsigned short* Q = qbuf + (size_t)bh * Sq * HD;
  const unsigned short* K = kbuf + (size_t)bh * Sq * HD;
  const unsigned short* Vt = vtbuf + (size_t)bh * HD * Sq;
  int b = bh >> 4, h = bh & 15;
  float4_t z = {0.f, 0.f, 0.f, 0.f};

  // --- K staging map (glds direct, 16B granule g ^= row&7) ---
  const int r0 = tid >> 3;                    // 0..31 (second call: +32)
  const int sgk = (tid & 7) ^ (r0 & 7);       // pre-swizzled source granule
  const unsigned short* kg = K + (size_t)r0 * HD + sgk * 8;  // += 64*HD per tile
  const int kdst = tid * 8;                   // linear dest (shorts)

  // --- V staging map (reg-staged, 8B slot d = w ^ (row&15)) ---
  const int w0 = (tid & 7) * 2;
  const int xa = r0 & 15;
  const int d0 = w0 ^ xa;                     // LDS slot holding content slot w0
  const unsigned short* vsrc = Vt + (size_t)r0 * Sq + w0 * 4;  // += 64 per tile
  const int vdst = r0 * 64 + d0 * 4;          // shorts; partner slot = vdst ^ 4

  // --- swizzled read offsets ---
  const int koff0 = (quad ^ lc7) * 8;
  const int koff1 = ((quad | 4) ^ lc7) * 8;
  int voff[4];
#pragma unroll
  for (int s4 = 0; s4 < 4; ++s4) voff[s4] = ((s4 * 4 + quad) ^ lcol) * 4;

  unsigned short* lkc = lk;
  unsigned short* lkn = lk + 4096;
  unsigned short* lvc = lv;
  unsigned short* lvn = lv + 4096;

  int q0w = ti * 64 + wave * 16;
  int q_global = q0w + lcol;
  short8_t qf0 = *(const short8_t*)(Q + (size_t)(q0w + lcol) * HD + quad * 8);
  short8_t qf1 = *(const short8_t*)(Q + (size_t)(q0w + lcol) * HD + 32 + quad * 8);
  float m_i = -INFINITY, l_i = 0.f;
  float4_t o[4];
#pragma unroll
  for (int f = 0; f < 4; ++f) o[f] = z;

  // --- prologue: stage tile 0 into current buffers ---
  {
    GLOAD_LDS16(kg, lkc + kdst);
    GLOAD_LDS16(kg + (size_t)32 * HD, lkc + 2048 + kdst);
    short4_t a0 = *(const short4_t*)(vsrc);
    short4_t a1 = *(const short4_t*)(vsrc + 4);
    short4_t b0 = *(const short4_t*)(vsrc + (size_t)32 * Sq);
    short4_t b1 = *(const short4_t*)(vsrc + (size_t)32 * Sq + 4);
    *(short4_t*)(lvc + vdst) = a0;
    *(short4_t*)(lvc + (vdst ^ 4)) = a1;
    *(short4_t*)(lvc + vdst + 2048) = b0;
    *(short4_t*)(lvc + (vdst ^ 4) + 2048) = b1;
  }
  __syncthreads();

  int nkt = ti + 1;
  for (int kt = 0; kt < nkt; ++kt) {
    bool has_next = (kt + 1 < nkt);
    short4_t a0, a1, b0, b1;
    if (has_next) {
      const unsigned short* vs = vsrc + (size_t)(kt + 1) * 64;
      a0 = *(const short4_t*)(vs);
      a1 = *(const short4_t*)(vs + 4);
      b0 = *(const short4_t*)(vs + (size_t)32 * Sq);
      b1 = *(const short4_t*)(vs + (size_t)32 * Sq + 4);
      const unsigned short* kgn = kg + (size_t)(kt + 1) * 64 * HD;
      GLOAD_LDS16(kgn, lkn + kdst);
      GLOAD_LDS16(kgn + (size_t)32 * HD, lkn + 2048 + kdst);
    }

    // --- QK^T from lkc ---
    float s[16];
#pragma unroll
    for (int s4 = 0; s4 < 4; ++s4) {
      const unsigned short* kr = lkc + (s4 * 16 + lcol) * 64;
      short8_t kf0 = *(const short8_t*)(kr + koff0);
      short8_t kf1 = *(const short8_t*)(kr + koff1);
      float4_t st = z;
      st = __builtin_amdgcn_mfma_f32_16x16x32_bf16(kf0, qf0, st, 0, 0, 0);
      st = __builtin_amdgcn_mfma_f32_16x16x32_bf16(kf1, qf1, st, 0, 0, 0);
#pragma unroll
      for (int r = 0; r < 4; ++r) s[s4 * 4 + r] = st[r];
    }
    if (kt == ti) {  // diagonal tile: causal mask (uniform branch)
      int key0 = kt * 64;
#pragma unroll
      for (int s4 = 0; s4 < 4; ++s4)
#pragma unroll
        for (int r = 0; r < 4; ++r)
          if (key0 + s4 * 16 + quad * 4 + r > q_global) s[s4 * 4 + r] = -INFINITY;
    }

    // max3-tree reduction over 16 values
    float ta = m3(s[0], s[1], s[2]);
    float tb = m3(s[3], s[4], s[5]);
    float tc = m3(s[6], s[7], s[8]);
    float td = m3(s[9], s[10], s[11]);
    float te = m3(s[12], s[13], s[14]);
    float tmax = m3(ta, tb, tc);
    tmax = m3(tmax, td, te);
    tmax = fmaxf(tmax, s[15]);
    tmax = fmaxf(tmax, __shfl_xor(tmax, 16, 64));
    tmax = fmaxf(tmax, __shfl_xor(tmax, 32, 64));

    // T13 defer-max (log2 domain, THR=8 -> P bounded by 256)
    if (__any(tmax > m_i + 8.f)) {
      float m_new = fmaxf(m_i, tmax);
      float alpha = exp2_fast(m_i - m_new);
      l_i *= alpha;
      m_i = m_new;
      float at[4];
#pragma unroll
      for (int r = 0; r < 4; ++r) at[r] = __shfl(alpha, quad * 4 + r, 64);
#pragma unroll
      for (int f = 0; f < 4; ++f)
#pragma unroll
        for (int r = 0; r < 4; ++r) o[f][r] *= at[r];
    }

    float psum = 0.f;
    short4_t pf[4];
#pragma unroll
    for (int s4 = 0; s4 < 4; ++s4) {
      float p0 = exp2_fast(s[s4 * 4 + 0] - m_i);
      float p1 = exp2_fast(s[s4 * 4 + 1] - m_i);
      float p2 = exp2_fast(s[s4 * 4 + 2] - m_i);
      float p3 = exp2_fast(s[s4 * 4 + 3] - m_i);
      psum += (p0 + p1) + (p2 + p3);
      unsigned lo, hi;
      asm("v_cvt_pk_bf16_f32 %0, %1, %2" : "=v"(lo) : "v"(p0), "v"(p1));
      asm("v_cvt_pk_bf16_f32 %0, %1, %2" : "=v"(hi) : "v"(p2), "v"(p3));
      uint2 packed;
      packed.x = lo;
      packed.y = hi;
      pf[s4] = __builtin_bit_cast(short4_t, packed);
    }
    psum += __shfl_xor(psum, 16, 64);
    psum += __shfl_xor(psum, 32, 64);
    l_i += psum;

    // --- write next-tile V into alternate buffer (vmcnt wait was hidden above) ---
    if (has_next) {
      *(short4_t*)(lvn + vdst) = a0;
      *(short4_t*)(lvn + (vdst ^ 4)) = a1;
      *(short4_t*)(lvn + vdst + 2048) = b0;
      *(short4_t*)(lvn + (vdst ^ 4) + 2048) = b1;
    }

    // --- PV from lvc (conflict-free swizzled b64 reads) ---
#pragma unroll
    for (int f = 0; f < 4; ++f) {
      const unsigned short* vr = lvc + (f * 16 + lcol) * 64;
#pragma unroll
      for (int s4 = 0; s4 < 4; ++s4) {
        short4_t vf = *(const short4_t*)(vr + voff[s4]);
        o[f] = __builtin_amdgcn_mfma_f32_16x16x16bf16_1k(pf[s4], vf, o[f], 0, 0, 0);
      }
    }

    __syncthreads();  // drains K glds (vmcnt0) + V ds_writes; buffers swap
    unsigned short* t;
    t = lkc; lkc = lkn; lkn = t;
    t = lvc; lvc = lvn; lvn = t;
  }

  float lt[4];
#pragma unroll
  for (int r = 0; r < 4; ++r) lt[r] = 1.f / __shfl(l_i, quad * 4 + r, 64);
#pragma unroll
  for (int f = 0; f < 4; ++f)
#pragma unroll
    for (int r = 0; r < 4; ++r) {
      int q = q0w + quad * 4 + r;
      int hd = f * 16 + lcol;
      ao[((size_t)b * Sq + q) * (NH * HD) + h * HD + hd] = f2bf(o[f][r] * lt[r]);
    }
}

extern "C" void kernel_launch(void* const* d_in, const int* in_sizes, int n_in,
                              void* d_out, int out_size, void* d_ws, size_t ws_size,
                              hipStream_t stream) {
  const float* x = (const float*)d_in[0];
  const float* Wq = (const float*)d_in[1];
  const float* Wk = (const float*)d_in[2];
  const float* Wv = (const float*)d_in[3];
  const float* Wo = (const float*)d_in[4];
  float* out = (float*)d_out;

  char* ws = (char*)d_ws;
  size_t off = 0;
  auto carve = [&](size_t bytes) {
    void* p = ws + off;
    off += (bytes + 255) & ~(size_t)255;
    return p;
  };
  const size_t xe = (size_t)Bz * Sq * Dm;
  const size_t we = (size_t)Dm * Dm;
  unsigned short* xb = (unsigned short*)carve(xe * 2);
  unsigned short* wqT = (unsigned short*)carve(we * 2);
  unsigned short* wkT = (unsigned short*)carve(we * 2);
  unsigned short* wvT = (unsigned short*)carve(we * 2);
  unsigned short* woT = (unsigned short*)carve(we * 2);
  unsigned short* qb = (unsigned short*)carve(xe * 2);
  unsigned short* kb = (unsigned short*)carve(xe * 2);
  unsigned short* vt = (unsigned short*)carve(xe * 2);
  unsigned short* ao = (unsigned short*)carve(xe * 2);
  (void)ws_size;

  cast_x_kernel<<<xe / 4 / 256, 256, 0, stream>>>(x, xb);
  transpose_w_kernel<<<dim3(16, 16, 4), 256, 0, stream>>>(Wq, Wk, Wv, Wo,
                                                          wqT, wkT, wvT, woT);
  gemm_qkv_kernel<<<dim3(8, 64, 3), 256, 0, stream>>>(xb, wqT, wkT, wvT, qb, kb, vt);
  attn_kernel<<<dim3(Bz * NH, 32), 256, 0, stream>>>(qb, kb, vt, ao);
  gemm_out_kernel<<<dim3(8, 64), 256, 0, stream>>>(ao, woT, out);
}